// Round 8
// baseline (1474.105 us; speedup 1.0000x reference)
//
#include <hip/hip_runtime.h>
#include <hip/hip_bf16.h>

#define EDGES 50000
#define NODES 10000

typedef __hip_bfloat16 bf16;
typedef __attribute__((ext_vector_type(8))) short bf16x8v;  // 8 bf16 = 4 VGPR (MFMA A/B frag)
typedef __attribute__((ext_vector_type(4))) float f32x4;    // MFMA C/D frag

__device__ __forceinline__ float bf2f(bf16 v){ return __bfloat162float(v); }
__device__ __forceinline__ bf16  f2bf(float v){ return __float2bfloat16(v); }
__device__ __forceinline__ unsigned short f2bfu(float f){
  bf16 h = __float2bfloat16(f);
  union{ bf16 h; unsigned short s; } u; u.h = h; return u.s;
}
__device__ __forceinline__ float silu_f(float v){ return v * (1.0f/(1.0f+__expf(-v))); }

// packed bf16x2 multiply (for staging: xs = msg * rad)
__device__ __forceinline__ unsigned mul1(unsigned a, unsigned b){
  union{unsigned u; float f;} a0,a1,b0,b1;
  a0.u = (a & 0xffffu) << 16; a1.u = a & 0xffff0000u;
  b0.u = (b & 0xffffu) << 16; b1.u = b & 0xffff0000u;
  float p0 = a0.f*b0.f, p1 = a1.f*b1.f;
  return (unsigned)f2bfu(p0) | ((unsigned)f2bfu(p1) << 16);
}
__device__ __forceinline__ uint4 mulp(uint4 a, uint4 b){
  uint4 r; r.x=mul1(a.x,b.x); r.y=mul1(a.y,b.y); r.z=mul1(a.z,b.z); r.w=mul1(a.w,b.w); return r;
}

// ---------------------------------------------------------------------------
// K0: weight prep — w[K][N] f32  ->  wt[N][K] bf16  (B-frags become 16B rows)
// ---------------------------------------------------------------------------
__global__ __launch_bounds__(256)
void k_wT(const float* __restrict__ w, bf16* __restrict__ wt, int K, int N){
  __shared__ float tile[32][33];
  const int kb = blockIdx.x*32, nb = blockIdx.y*32;
  const int tx = threadIdx.x & 31, ty = threadIdx.x >> 5;   // 32 x 8
#pragma unroll
  for (int i=0;i<32;i+=8) tile[ty+i][tx] = w[(size_t)(kb+ty+i)*N + nb+tx];
  __syncthreads();
#pragma unroll
  for (int i=0;i<32;i+=8) wt[(size_t)(nb+ty+i)*K + kb+tx] = f2bf(tile[tx][ty+i]);
}

// ---------------------------------------------------------------------------
// K1: msg[e] = wigner[e] @ x[src[e]]   (9x9 @ 9x128), write bf16
// ---------------------------------------------------------------------------
__global__ __launch_bounds__(128)
void k_gather_rot(const float* __restrict__ x, const int* __restrict__ eidx,
                  const float* __restrict__ wig, bf16* __restrict__ msg)
{
  const int e = blockIdx.x;
  const int c = threadIdx.x;
  __shared__ float wl[81];
  if (c < 81) wl[c] = wig[e*81 + c];
  const int src = eidx[e];
  const float* xp = x + (size_t)src*1152 + c;
  float xr[9];
#pragma unroll
  for (int f=0; f<9; ++f) xr[f] = xp[f*128];
  __syncthreads();
  bf16* mp = msg + (size_t)e*1152 + c;
#pragma unroll
  for (int fo=0; fo<9; ++fo){
    float a = 0.f;
#pragma unroll
    for (int f=0; f<9; ++f) a = fmaf(wl[fo*9+f], xr[f], a);
    mp[fo*128] = f2bf(a);
  }
}

// ---------------------------------------------------------------------------
// K2: rad[e] = silu(LN(x_edge@w1+b1))@w2 + b2   (one radial, TE=16)
// ---------------------------------------------------------------------------
__global__ __launch_bounds__(256)
void k_radial(const float* __restrict__ x_edge,
              const float* __restrict__ w1, const float* __restrict__ b1,
              const float* __restrict__ gm, const float* __restrict__ bt,
              const float* __restrict__ w2, const float* __restrict__ b2,
              bf16* __restrict__ ro)
{
  __shared__ float xe[16][128];
  __shared__ float h[16][128];
  __shared__ float mu_s[16], rs_s[16];
  const int t = threadIdx.x;
  const int e0 = blockIdx.x * 16;
  for (int i=0;i<8;++i){
    int lin = t + 256*i;
    int e = lin >> 7, j2 = lin & 127;
    xe[e][j2] = x_edge[(size_t)(e0+e)*128 + j2];
  }
  __syncthreads();
  const int j = t & 127, g = t >> 7;
  {
    float acc[8] = {0,0,0,0,0,0,0,0};
    for (int k=0;k<128;k+=4){
      float wv0 = w1[(k+0)*128+j];
      float wv1 = w1[(k+1)*128+j];
      float wv2 = w1[(k+2)*128+j];
      float wv3 = w1[(k+3)*128+j];
#pragma unroll
      for (int e=0;e<8;++e){
        float4 xv = *(const float4*)&xe[g*8+e][k];
        acc[e] += xv.x*wv0 + xv.y*wv1 + xv.z*wv2 + xv.w*wv3;
      }
    }
    float bv = b1[j];
#pragma unroll
    for (int e=0;e<8;++e) h[g*8+e][j] = acc[e] + bv;
  }
  __syncthreads();
  {
    int e = t >> 4, p = t & 15;
    float s=0.f, ss=0.f;
#pragma unroll
    for (int i=0;i<8;++i){ float v = h[e][p+16*i]; s += v; ss += v*v; }
#pragma unroll
    for (int off=8; off>0; off>>=1){ s += __shfl_xor(s, off, 16); ss += __shfl_xor(ss, off, 16); }
    if (p==0){
      float m = s*(1.f/128.f);
      mu_s[e] = m;
      rs_s[e] = rsqrtf(fmaxf(ss*(1.f/128.f)-m*m, 0.f) + 1e-5f);
    }
  }
  __syncthreads();
  {
    float gv = gm[j], bv = bt[j];
#pragma unroll
    for (int e=0;e<8;++e){
      int ee = g*8+e;
      float v = (h[ee][j]-mu_s[ee])*rs_s[ee]*gv + bv;
      h[ee][j] = silu_f(v);
    }
  }
  __syncthreads();
  if (t < 192){
    int col = t*4;
    float acc[16][4];
#pragma unroll
    for (int e=0;e<16;++e){ acc[e][0]=acc[e][1]=acc[e][2]=acc[e][3]=0.f; }
    for (int k=0;k<128;k+=4){
      float4 wv0 = *(const float4*)&w2[(k+0)*768+col];
      float4 wv1 = *(const float4*)&w2[(k+1)*768+col];
      float4 wv2 = *(const float4*)&w2[(k+2)*768+col];
      float4 wv3 = *(const float4*)&w2[(k+3)*768+col];
#pragma unroll
      for (int e=0;e<16;++e){
        float4 hv = *(const float4*)&h[e][k];
        acc[e][0] += hv.x*wv0.x + hv.y*wv1.x + hv.z*wv2.x + hv.w*wv3.x;
        acc[e][1] += hv.x*wv0.y + hv.y*wv1.y + hv.z*wv2.y + hv.w*wv3.y;
        acc[e][2] += hv.x*wv0.z + hv.y*wv1.z + hv.z*wv2.z + hv.w*wv3.z;
        acc[e][3] += hv.x*wv0.w + hv.y*wv1.w + hv.z*wv2.w + hv.w*wv3.w;
      }
    }
    float4 bv = *(const float4*)&b2[col];
#pragma unroll
    for (int e=0;e<16;++e){
      ushort4 pk;
      pk.x = f2bfu(acc[e][0]+bv.x);
      pk.y = f2bfu(acc[e][1]+bv.y);
      pk.z = f2bfu(acc[e][2]+bv.z);
      pk.w = f2bfu(acc[e][3]+bv.w);
      *reinterpret_cast<ushort4*>(&ro[(size_t)(e0+e)*768 + col]) = pk;
    }
  }
}

// ---------------------------------------------------------------------------
// K3/K4: SO2 conv via MFMA. 32 edges/block, 4 waves, in-place on msg.
// Round-6 PMC showed latency-bound (MfmaUtil 5%, VALU 9%, HBM 10%): staging
// phases serialized behind barriers with ~2 loads in flight. This version:
//  - register-batched staging loads (all of a phase's loads issued together)
//  - T14 prefetch: A1.half0 loads in flight during G0; A1.half1 during
//    epilogue0; A2 loads during G1.
// LDS unchanged: bufA 32KB + gls 16KB = 48KB -> 3 blk/CU.
// ---------------------------------------------------------------------------
template<bool CONV1>
__global__ __launch_bounds__(256, 3)
void k_so2_mfma(const bf16* __restrict__ rad,
                const bf16* __restrict__ w0t, const float* __restrict__ b0,
                const bf16* __restrict__ w1t, const bf16* __restrict__ w2t,
                bf16* __restrict__ msg)
{
  __shared__ char ldsA[32768];
  __shared__ bf16 gls[8192];          // [32 edges][256] silu(gating), conv1 only
  const int t    = threadIdx.x;
  const int lane = t & 63, wv = t >> 6;
  const int lrow = lane & 15, lhi = lane >> 4;
  const int e0 = blockIdx.x * 32;
  int evalid = EDGES - e0; if (evalid > 32) evalid = 32;
  const uint4 z4 = {0u,0u,0u,0u};

  // ---- A0 loads, register-batched (12 loads in flight) ----
  uint4 mz0[6], rz0[6];
#pragma unroll
  for (int i=0;i<6;++i){
    int ch = t + 256*i;                       // 0..1535
    int row = ch / 48, k0 = (ch % 48) * 8;
    int e = e0 + row;
    mz0[i] = z4; rz0[i] = z4;
    if (e < EDGES){
      mz0[i] = *(const uint4*)(msg + (size_t)e*1152 + k0);
      rz0[i] = *(const uint4*)(rad + (size_t)e*768  + k0);
    }
  }
#pragma unroll
  for (int i=0;i<6;++i){
    int ch = t + 256*i;
    int row = ch / 48, k0 = (ch % 48) * 8;
    *(uint4*)(ldsA + ((row*768 + k0*2) ^ ((row&7)<<4))) = mulp(mz0[i], rz0[i]);
  }

  // ---- A1.half0 loads issued now: in flight across G0 ----
  uint4 mz1[4], rz1[4];
#pragma unroll
  for (int i=0;i<4;++i){
    int ch = t + 256*i;                       // 0..1023 -> rows 0..31
    int row = ch >> 5, k0 = (ch & 31) * 8;
    int e = e0 + (row >> 1);
    mz1[i] = z4; rz1[i] = z4;
    if (e < EDGES){
      mz1[i] = *(const uint4*)(msg + (size_t)e*1152 + 384 + (row&1)*256 + k0);
      rz1[i] = *(const uint4*)(rad + (size_t)e*768  + 384 + k0);
    }
  }
  __syncthreads();                            // A0 ready

  // ---- G0: K=384, N0 cols split 4 waves ----
  constexpr int NT0 = CONV1 ? 10 : 6;         // 16-col tiles per wave
  const int wcol0 = wv * NT0 * 16;
  f32x4 acc0[NT0][2];
  const f32x4 zf = {0.f,0.f,0.f,0.f};
#pragma unroll
  for (int nt=0; nt<NT0; ++nt){ acc0[nt][0]=zf; acc0[nt][1]=zf; }
  for (int ks=0; ks<12; ++ks){
    bf16x8v a0 = *(const bf16x8v*)(ldsA + (((lrow   )*768 + ks*64 + lhi*16) ^ ((lrow&7)<<4)));
    bf16x8v a1 = *(const bf16x8v*)(ldsA + (((16+lrow)*768 + ks*64 + lhi*16) ^ ((lrow&7)<<4)));
#pragma unroll
    for (int nt=0; nt<NT0; ++nt){
      int coln = wcol0 + nt*16 + lrow;
      bf16x8v b = *(const bf16x8v*)(w0t + (size_t)coln*384 + ks*32 + lhi*8);
      acc0[nt][0] = __builtin_amdgcn_mfma_f32_16x16x32_bf16(a0, b, acc0[nt][0], 0,0,0);
      acc0[nt][1] = __builtin_amdgcn_mfma_f32_16x16x32_bf16(a1, b, acc0[nt][1], 0,0,0);
    }
  }
  // gate cols -> gls (conv1)
  if (CONV1){
#pragma unroll
    for (int nt=0; nt<NT0; ++nt){
      int colb = wcol0 + nt*16;
      if (colb >= 384){
        float bc = b0[colb + lrow];
#pragma unroll
        for (int mt=0; mt<2; ++mt)
#pragma unroll
        for (int r=0; r<4; ++r){
          int el = mt*16 + lhi*4 + r;
          gls[el*256 + colb + lrow - 384] = f2bf(silu_f(acc0[nt][mt][r] + bc));
        }
      }
    }
  }
  __syncthreads();                            // gls ready; G0 LDS reads done

  // ---- A1.half1 loads issued now: latency hidden by epilogue0 stores ----
  uint4 mz1b[4], rz1b[4];
#pragma unroll
  for (int i=0;i<4;++i){
    int ch = t + 256*i + 1024;                // rows 32..63
    int row = ch >> 5, k0 = (ch & 31) * 8;
    int e = e0 + (row >> 1);
    mz1b[i] = z4; rz1b[i] = z4;
    if (e < EDGES){
      mz1b[i] = *(const uint4*)(msg + (size_t)e*1152 + 384 + (row&1)*256 + k0);
      rz1b[i] = *(const uint4*)(rad + (size_t)e*768  + 384 + k0);
    }
  }

  // out0 epilogue (rows 0-2)
#pragma unroll
  for (int nt=0; nt<NT0; ++nt){
    int colb = wcol0 + nt*16;
    if (colb < 384){
      int col = colb + lrow;
      int f = col >> 7, c = col & 127;
      float bc = b0[col];
#pragma unroll
      for (int mt=0; mt<2; ++mt)
#pragma unroll
      for (int r=0; r<4; ++r){
        int el = mt*16 + lhi*4 + r;
        if (el < evalid){
          float v = acc0[nt][mt][r] + bc;
          float o;
          if (CONV1) o = (f==0) ? silu_f(v) : v * bf2f(gls[el*256 + (f==2?128:0) + c]);
          else       o = v;
          msg[(size_t)(e0+el)*1152 + col] = f2bf(o);
        }
      }
    }
  }

  // ---- A1 writes to LDS (safe: barrier above ended all G0 LDS reads) ----
#pragma unroll
  for (int i=0;i<4;++i){
    int ch = t + 256*i;
    int row = ch >> 5, k0 = (ch & 31) * 8;
    *(uint4*)(ldsA + ((row*512 + k0*2) ^ ((row&7)<<4))) = mulp(mz1[i], rz1[i]);
  }
#pragma unroll
  for (int i=0;i<4;++i){
    int ch = t + 256*i + 1024;
    int row = ch >> 5, k0 = (ch & 31) * 8;
    *(uint4*)(ldsA + ((row*512 + k0*2) ^ ((row&7)<<4))) = mulp(mz1b[i], rz1b[i]);
  }

  // ---- A2 loads issued now: in flight across G1 ----
  uint4 mz2[4], rz2[4];
#pragma unroll
  for (int i=0;i<4;++i){
    int ch = t + 256*i;                       // 0..1023
    int row = ch >> 4, k0 = (ch & 15) * 8;
    int e = e0 + (row >> 1);
    mz2[i] = z4; rz2[i] = z4;
    if (e < EDGES){
      mz2[i] = *(const uint4*)(msg + (size_t)e*1152 + 896 + (row&1)*128 + k0);
      rz2[i] = *(const uint4*)(rad + (size_t)e*768  + 640 + k0);
    }
  }
  __syncthreads();                            // A1 ready

  // ---- G1: K=256, N=512, col pairs (jj, jj+256); 4 pairs/wave; mtiles 2+2 ----
#pragma unroll
  for (int half=0; half<2; ++half){
    f32x4 acc1[4][2][2];
#pragma unroll
    for (int p=0;p<4;++p){ acc1[p][0][0]=zf; acc1[p][0][1]=zf; acc1[p][1][0]=zf; acc1[p][1][1]=zf; }
    for (int ks=0; ks<8; ++ks){
      bf16x8v aA[2];
#pragma unroll
      for (int m2=0; m2<2; ++m2){
        int row = (half*2+m2)*16 + lrow;
        aA[m2] = *(const bf16x8v*)(ldsA + ((row*512 + ks*64 + lhi*16) ^ ((row&7)<<4)));
      }
#pragma unroll
      for (int p=0; p<4; ++p){
        int jj = wv*64 + p*16 + lrow;
        bf16x8v br = *(const bf16x8v*)(w1t + (size_t)jj*256       + ks*32 + lhi*8);
        bf16x8v bi = *(const bf16x8v*)(w1t + (size_t)(jj+256)*256 + ks*32 + lhi*8);
#pragma unroll
        for (int m2=0;m2<2;++m2){
          acc1[p][m2][0] = __builtin_amdgcn_mfma_f32_16x16x32_bf16(aA[m2], br, acc1[p][m2][0], 0,0,0);
          acc1[p][m2][1] = __builtin_amdgcn_mfma_f32_16x16x32_bf16(aA[m2], bi, acc1[p][m2][1], 0,0,0);
        }
      }
    }
    // epilogue rows 3-6: o0=r0-i1 -> 384+jj ; o1=r1+i0 -> 640+jj
#pragma unroll
    for (int p=0;p<4;++p)
#pragma unroll
    for (int m2=0;m2<2;++m2){
      int mt = half*2 + m2;
#pragma unroll
      for (int re=0;re<2;++re){
        int el = mt*8 + lhi*2 + re;
        float r0 = acc1[p][m2][0][2*re+0], r1 = acc1[p][m2][0][2*re+1];
        float i0 = acc1[p][m2][1][2*re+0], i1 = acc1[p][m2][1][2*re+1];
        float o0 = r0 - i1, o1 = r1 + i0;
        int jj = wv*64 + p*16 + lrow;
        if (CONV1){ float g = bf2f(gls[el*256 + jj]); o0 *= g; o1 *= g; }
        if (el < evalid){
          size_t base = (size_t)(e0+el)*1152;
          msg[base + 384 + jj] = f2bf(o0);
          msg[base + 640 + jj] = f2bf(o1);
        }
      }
    }
  }
  __syncthreads();                            // G1 LDS reads done

  // ---- A2 writes ----
#pragma unroll
  for (int i=0;i<4;++i){
    int ch = t + 256*i;
    int row = ch >> 4, k0 = (ch & 15) * 8;
    *(uint4*)(ldsA + ((row*256 + k0*2) ^ ((row&7)<<4))) = mulp(mz2[i], rz2[i]);
  }
  __syncthreads();                            // A2 ready

  // ---- G2: K=128, N=256, col pairs (jj, jj+128); 2 pairs/wave; 4 mtiles ----
  {
    f32x4 acc2[2][4][2];
#pragma unroll
    for (int p=0;p<2;++p)
#pragma unroll
    for (int mt=0;mt<4;++mt){ acc2[p][mt][0]=zf; acc2[p][mt][1]=zf; }
    for (int ks=0; ks<4; ++ks){
      bf16x8v aA[4];
#pragma unroll
      for (int mt=0;mt<4;++mt){
        int row = mt*16 + lrow;
        aA[mt] = *(const bf16x8v*)(ldsA + ((row*256 + ks*64 + lhi*16) ^ ((row&7)<<4)));
      }
#pragma unroll
      for (int p=0;p<2;++p){
        int jj = wv*32 + p*16 + lrow;
        bf16x8v br = *(const bf16x8v*)(w2t + (size_t)jj*128       + ks*32 + lhi*8);
        bf16x8v bi = *(const bf16x8v*)(w2t + (size_t)(jj+128)*128 + ks*32 + lhi*8);
#pragma unroll
        for (int mt=0;mt<4;++mt){
          acc2[p][mt][0] = __builtin_amdgcn_mfma_f32_16x16x32_bf16(aA[mt], br, acc2[p][mt][0], 0,0,0);
          acc2[p][mt][1] = __builtin_amdgcn_mfma_f32_16x16x32_bf16(aA[mt], bi, acc2[p][mt][1], 0,0,0);
        }
      }
    }
    // epilogue rows 7,8
#pragma unroll
    for (int p=0;p<2;++p)
#pragma unroll
    for (int mt=0;mt<4;++mt)
#pragma unroll
    for (int re=0;re<2;++re){
      int el = mt*8 + lhi*2 + re;
      float r0 = acc2[p][mt][0][2*re+0], r1 = acc2[p][mt][0][2*re+1];
      float i0 = acc2[p][mt][1][2*re+0], i1 = acc2[p][mt][1][2*re+1];
      float o0 = r0 - i1, o1 = r1 + i0;
      int jj = wv*32 + p*16 + lrow;
      if (CONV1){ float g = bf2f(gls[el*256 + 128 + jj]); o0 *= g; o1 *= g; }
      if (el < evalid){
        size_t base = (size_t)(e0+el)*1152;
        msg[base + 896  + jj] = f2bf(o0);
        msg[base + 1024 + jj] = f2bf(o1);
      }
    }
  }
}

// ---------------------------------------------------------------------------
// K5: out[dst] += wigner_inv[e] @ msg[e]
// ---------------------------------------------------------------------------
__global__ __launch_bounds__(128)
void k_wiginv_scatter(const bf16* __restrict__ msg, const int* __restrict__ eidx,
                      const float* __restrict__ wiginv, float* __restrict__ out)
{
  const int e = blockIdx.x;
  const int c = threadIdx.x;
  __shared__ float wl[81];
  if (c < 81) wl[c] = wiginv[e*81 + c];
  float m[9];
#pragma unroll
  for (int r=0;r<9;++r) m[r] = bf2f(msg[(size_t)e*1152 + r*128 + c]);
  const int dst = eidx[EDGES + e];
  __syncthreads();
  float* op = out + (size_t)dst*1152 + c;
#pragma unroll
  for (int f=0;f<9;++f){
    float a = 0.f;
#pragma unroll
    for (int r=0;r<9;++r) a = fmaf(wl[f*9+r], m[r], a);
    atomicAdd(op + f*128, a);
  }
}

// ---------------------------------------------------------------------------
extern "C" void kernel_launch(void* const* d_in, const int* in_sizes, int n_in,
                              void* d_out, int out_size, void* d_ws, size_t ws_size,
                              hipStream_t stream)
{
  const float* x       = (const float*)d_in[0];
  const float* x_edge  = (const float*)d_in[1];
  const int*   eidx    = (const int*)  d_in[3];
  const float* wig     = (const float*)d_in[4];
  const float* wiginv  = (const float*)d_in[5];
  const float* r1w1    = (const float*)d_in[6];
  const float* r1b1    = (const float*)d_in[7];
  const float* r1g     = (const float*)d_in[8];
  const float* r1bt    = (const float*)d_in[9];
  const float* r1w2    = (const float*)d_in[10];
  const float* r1b2    = (const float*)d_in[11];
  const float* c1w0    = (const float*)d_in[12];
  const float* c1b0    = (const float*)d_in[13];
  const float* c1w1    = (const float*)d_in[14];
  const float* c1w2    = (const float*)d_in[15];
  const float* r2w1    = (const float*)d_in[16];
  const float* r2b1    = (const float*)d_in[17];
  const float* r2g     = (const float*)d_in[18];
  const float* r2bt    = (const float*)d_in[19];
  const float* r2w2    = (const float*)d_in[20];
  const float* r2b2    = (const float*)d_in[21];
  const float* c2w0    = (const float*)d_in[22];
  const float* c2b0    = (const float*)d_in[23];
  const float* c2w1    = (const float*)d_in[24];
  const float* c2w2    = (const float*)d_in[25];
  float* out = (float*)d_out;

  // ws layout: msg 115.2MB | rad 76.8MB | bf16 [N][K] weights ~1.44MB  (<=193.5MB)
  char* ws = (char*)d_ws;
  bf16* msg  = (bf16*)(ws);
  bf16* rad  = (bf16*)(ws + (size_t)115200000);
  bf16* w0t1 = (bf16*)(ws + (size_t)192000000);   // 640x384
  bf16* w1t1 = (bf16*)(ws + (size_t)192491520);   // 512x256
  bf16* w2t1 = (bf16*)(ws + (size_t)192753664);   // 256x128
  bf16* w0t2 = (bf16*)(ws + (size_t)192819200);   // 384x384
  bf16* w1t2 = (bf16*)(ws + (size_t)193114112);   // 512x256
  bf16* w2t2 = (bf16*)(ws + (size_t)193376256);   // 256x128

  k_wT<<<dim3(12,20),256,0,stream>>>(c1w0, w0t1, 384, 640);
  k_wT<<<dim3( 8,16),256,0,stream>>>(c1w1, w1t1, 256, 512);
  k_wT<<<dim3( 4, 8),256,0,stream>>>(c1w2, w2t1, 128, 256);
  k_wT<<<dim3(12,12),256,0,stream>>>(c2w0, w0t2, 384, 384);
  k_wT<<<dim3( 8,16),256,0,stream>>>(c2w1, w1t2, 256, 512);
  k_wT<<<dim3( 4, 8),256,0,stream>>>(c2w2, w2t2, 128, 256);

  hipMemsetAsync(d_out, 0, (size_t)out_size*sizeof(float), stream);
  k_gather_rot<<<EDGES, 128, 0, stream>>>(x, eidx, wig, msg);
  k_radial<<<EDGES/16, 256, 0, stream>>>(x_edge, r1w1, r1b1, r1g, r1bt, r1w2, r1b2, rad);
  k_so2_mfma<true ><<<(EDGES+31)/32, 256, 0, stream>>>(rad, w0t1, c1b0, w1t1, w2t1, msg);
  k_radial<<<EDGES/16, 256, 0, stream>>>(x_edge, r2w1, r2b1, r2g, r2bt, r2w2, r2b2, rad);
  k_so2_mfma<false><<<(EDGES+31)/32, 256, 0, stream>>>(rad, w0t2, c2b0, w1t2, w2t2, msg);
  k_wiginv_scatter<<<EDGES, 128, 0, stream>>>(msg, eidx, wiginv, out);
}

// Round 9
// 1460.709 us; speedup vs baseline: 1.0092x; 1.0092x over previous
//
#include <hip/hip_runtime.h>
#include <hip/hip_bf16.h>

#define EDGES 50000
#define NODES 10000

typedef __hip_bfloat16 bf16;
typedef __attribute__((ext_vector_type(8))) short bf16x8v;  // 8 bf16 = 4 VGPR (MFMA A/B frag)
typedef __attribute__((ext_vector_type(4))) float f32x4;    // MFMA C/D frag

__device__ __forceinline__ float bf2f(bf16 v){ return __bfloat162float(v); }
__device__ __forceinline__ bf16  f2bf(float v){ return __float2bfloat16(v); }
__device__ __forceinline__ unsigned short f2bfu(float f){
  bf16 h = __float2bfloat16(f);
  union{ bf16 h; unsigned short s; } u; u.h = h; return u.s;
}
__device__ __forceinline__ float silu_f(float v){ return v * (1.0f/(1.0f+__expf(-v))); }

// packed bf16x2 multiply (for staging: xs = msg * rad)
__device__ __forceinline__ unsigned mul1(unsigned a, unsigned b){
  union{unsigned u; float f;} a0,a1,b0,b1;
  a0.u = (a & 0xffffu) << 16; a1.u = a & 0xffff0000u;
  b0.u = (b & 0xffffu) << 16; b1.u = b & 0xffff0000u;
  float p0 = a0.f*b0.f, p1 = a1.f*b1.f;
  return (unsigned)f2bfu(p0) | ((unsigned)f2bfu(p1) << 16);
}
__device__ __forceinline__ uint4 mulp(uint4 a, uint4 b){
  uint4 r; r.x=mul1(a.x,b.x); r.y=mul1(a.y,b.y); r.z=mul1(a.z,b.z); r.w=mul1(a.w,b.w); return r;
}

// ---------------------------------------------------------------------------
// K0: weight prep — w[K][N] f32  ->  wt[N][K] bf16
// ---------------------------------------------------------------------------
__global__ __launch_bounds__(256)
void k_wT(const float* __restrict__ w, bf16* __restrict__ wt, int K, int N){
  __shared__ float tile[32][33];
  const int kb = blockIdx.x*32, nb = blockIdx.y*32;
  const int tx = threadIdx.x & 31, ty = threadIdx.x >> 5;   // 32 x 8
#pragma unroll
  for (int i=0;i<32;i+=8) tile[ty+i][tx] = w[(size_t)(kb+ty+i)*N + nb+tx];
  __syncthreads();
#pragma unroll
  for (int i=0;i<32;i+=8) wt[(size_t)(nb+ty+i)*K + kb+tx] = f2bf(tile[tx][ty+i]);
}

// ---------------------------------------------------------------------------
// K1: msg[e] = wigner[e] @ x[src[e]]
// ---------------------------------------------------------------------------
__global__ __launch_bounds__(128)
void k_gather_rot(const float* __restrict__ x, const int* __restrict__ eidx,
                  const float* __restrict__ wig, bf16* __restrict__ msg)
{
  const int e = blockIdx.x;
  const int c = threadIdx.x;
  __shared__ float wl[81];
  if (c < 81) wl[c] = wig[e*81 + c];
  const int src = eidx[e];
  const float* xp = x + (size_t)src*1152 + c;
  float xr[9];
#pragma unroll
  for (int f=0; f<9; ++f) xr[f] = xp[f*128];
  __syncthreads();
  bf16* mp = msg + (size_t)e*1152 + c;
#pragma unroll
  for (int fo=0; fo<9; ++fo){
    float a = 0.f;
#pragma unroll
    for (int f=0; f<9; ++f) a = fmaf(wl[fo*9+f], xr[f], a);
    mp[fo*128] = f2bf(a);
  }
}

// ---------------------------------------------------------------------------
// K2: rad[e] = silu(LN(x_edge@w1+b1))@w2 + b2
// ---------------------------------------------------------------------------
__global__ __launch_bounds__(256)
void k_radial(const float* __restrict__ x_edge,
              const float* __restrict__ w1, const float* __restrict__ b1,
              const float* __restrict__ gm, const float* __restrict__ bt,
              const float* __restrict__ w2, const float* __restrict__ b2,
              bf16* __restrict__ ro)
{
  __shared__ float xe[16][128];
  __shared__ float h[16][128];
  __shared__ float mu_s[16], rs_s[16];
  const int t = threadIdx.x;
  const int e0 = blockIdx.x * 16;
  for (int i=0;i<8;++i){
    int lin = t + 256*i;
    int e = lin >> 7, j2 = lin & 127;
    xe[e][j2] = x_edge[(size_t)(e0+e)*128 + j2];
  }
  __syncthreads();
  const int j = t & 127, g = t >> 7;
  {
    float acc[8] = {0,0,0,0,0,0,0,0};
    for (int k=0;k<128;k+=4){
      float wv0 = w1[(k+0)*128+j];
      float wv1 = w1[(k+1)*128+j];
      float wv2 = w1[(k+2)*128+j];
      float wv3 = w1[(k+3)*128+j];
#pragma unroll
      for (int e=0;e<8;++e){
        float4 xv = *(const float4*)&xe[g*8+e][k];
        acc[e] += xv.x*wv0 + xv.y*wv1 + xv.z*wv2 + xv.w*wv3;
      }
    }
    float bv = b1[j];
#pragma unroll
    for (int e=0;e<8;++e) h[g*8+e][j] = acc[e] + bv;
  }
  __syncthreads();
  {
    int e = t >> 4, p = t & 15;
    float s=0.f, ss=0.f;
#pragma unroll
    for (int i=0;i<8;++i){ float v = h[e][p+16*i]; s += v; ss += v*v; }
#pragma unroll
    for (int off=8; off>0; off>>=1){ s += __shfl_xor(s, off, 16); ss += __shfl_xor(ss, off, 16); }
    if (p==0){
      float m = s*(1.f/128.f);
      mu_s[e] = m;
      rs_s[e] = rsqrtf(fmaxf(ss*(1.f/128.f)-m*m, 0.f) + 1e-5f);
    }
  }
  __syncthreads();
  {
    float gv = gm[j], bv = bt[j];
#pragma unroll
    for (int e=0;e<8;++e){
      int ee = g*8+e;
      float v = (h[ee][j]-mu_s[ee])*rs_s[ee]*gv + bv;
      h[ee][j] = silu_f(v);
    }
  }
  __syncthreads();
  if (t < 192){
    int col = t*4;
    float acc[16][4];
#pragma unroll
    for (int e=0;e<16;++e){ acc[e][0]=acc[e][1]=acc[e][2]=acc[e][3]=0.f; }
    for (int k=0;k<128;k+=4){
      float4 wv0 = *(const float4*)&w2[(k+0)*768+col];
      float4 wv1 = *(const float4*)&w2[(k+1)*768+col];
      float4 wv2 = *(const float4*)&w2[(k+2)*768+col];
      float4 wv3 = *(const float4*)&w2[(k+3)*768+col];
#pragma unroll
      for (int e=0;e<16;++e){
        float4 hv = *(const float4*)&h[e][k];
        acc[e][0] += hv.x*wv0.x + hv.y*wv1.x + hv.z*wv2.x + hv.w*wv3.x;
        acc[e][1] += hv.x*wv0.y + hv.y*wv1.y + hv.z*wv2.y + hv.w*wv3.y;
        acc[e][2] += hv.x*wv0.z + hv.y*wv1.z + hv.z*wv2.z + hv.w*wv3.z;
        acc[e][3] += hv.x*wv0.w + hv.y*wv1.w + hv.z*wv2.w + hv.w*wv3.w;
      }
    }
    float4 bv = *(const float4*)&b2[col];
#pragma unroll
    for (int e=0;e<16;++e){
      ushort4 pk;
      pk.x = f2bfu(acc[e][0]+bv.x);
      pk.y = f2bfu(acc[e][1]+bv.y);
      pk.z = f2bfu(acc[e][2]+bv.z);
      pk.w = f2bfu(acc[e][3]+bv.w);
      *reinterpret_cast<ushort4*>(&ro[(size_t)(e0+e)*768 + col]) = pk;
    }
  }
}

// ---------------------------------------------------------------------------
// K3/K4: SO2 conv via MFMA. 32 edges/block, 4 waves, in-place on msg.
// Round-8 PMC: MfmaUtil 5.3%, WRITE 292MB (2.5x logical) -> latency + write
// amplification. This version: (a) B-frags batch-loaded into register arrays
// (5/8/4 outstanding), (b) ALL msg stores coalesced via LDS-staged y buffers
// (full 16B/lane lines), (c) staging prefetch kept.
// LDS: ldsA 32KB (A-tiles / y-stages, phase-reused) + gls 16KB.
// ---------------------------------------------------------------------------
template<bool CONV1>
__global__ __launch_bounds__(256, 3)
void k_so2_mfma(const bf16* __restrict__ rad,
                const bf16* __restrict__ w0t, const float* __restrict__ b0,
                const bf16* __restrict__ w1t, const bf16* __restrict__ w2t,
                bf16* __restrict__ msg)
{
  __shared__ char ldsA[32768];
  __shared__ bf16 gls[8192];          // [32 edges][256] silu(gating), conv1 only
  const int t    = threadIdx.x;
  const int lane = t & 63, wv = t >> 6;
  const int lrow = lane & 15, lhi = lane >> 4;
  const int e0 = blockIdx.x * 32;
  int evalid = EDGES - e0; if (evalid > 32) evalid = 32;
  const uint4 z4 = {0u,0u,0u,0u};
  const f32x4 zf = {0.f,0.f,0.f,0.f};

  // ---- A0 loads (12 outstanding) ----
  uint4 mz0[6], rz0[6];
#pragma unroll
  for (int i=0;i<6;++i){
    int ch = t + 256*i;                       // 0..1535
    int row = ch / 48, k0 = (ch % 48) * 8;
    int e = e0 + row;
    mz0[i] = z4; rz0[i] = z4;
    if (e < EDGES){
      mz0[i] = *(const uint4*)(msg + (size_t)e*1152 + k0);
      rz0[i] = *(const uint4*)(rad + (size_t)e*768  + k0);
    }
  }
#pragma unroll
  for (int i=0;i<6;++i){
    int ch = t + 256*i;
    int row = ch / 48, k0 = (ch % 48) * 8;
    *(uint4*)(ldsA + ((row*768 + k0*2) ^ ((row&7)<<4))) = mulp(mz0[i], rz0[i]);
  }

  // ---- A1.half0 prefetch (in flight across G0) ----
  uint4 mz1[4], rz1[4];
#pragma unroll
  for (int i=0;i<4;++i){
    int ch = t + 256*i;                       // rows 0..31
    int row = ch >> 5, k0 = (ch & 31) * 8;
    int e = e0 + (row >> 1);
    mz1[i] = z4; rz1[i] = z4;
    if (e < EDGES){
      mz1[i] = *(const uint4*)(msg + (size_t)e*1152 + 384 + (row&1)*256 + k0);
      rz1[i] = *(const uint4*)(rad + (size_t)e*768  + 384 + k0);
    }
  }
  __syncthreads();                            // B1: A0 ready

  // ---- G0: K=384, N0 split 4 waves; B batched in halves ----
  constexpr int NT0 = CONV1 ? 10 : 6;
  constexpr int HB  = NT0 / 2;                // 5 or 3 outstanding B-loads
  const int wcol0 = wv * NT0 * 16;
  f32x4 acc0[NT0][2];
#pragma unroll
  for (int nt=0; nt<NT0; ++nt){ acc0[nt][0]=zf; acc0[nt][1]=zf; }
  for (int ks=0; ks<12; ++ks){
    bf16x8v a0 = *(const bf16x8v*)(ldsA + (((lrow   )*768 + ks*64 + lhi*16) ^ ((lrow&7)<<4)));
    bf16x8v a1 = *(const bf16x8v*)(ldsA + (((16+lrow)*768 + ks*64 + lhi*16) ^ ((lrow&7)<<4)));
#pragma unroll
    for (int h=0; h<2; ++h){
      bf16x8v bb[HB];
#pragma unroll
      for (int j=0;j<HB;++j){
        int coln = wcol0 + (h*HB+j)*16 + lrow;
        bb[j] = *(const bf16x8v*)(w0t + (size_t)coln*384 + ks*32 + lhi*8);
      }
#pragma unroll
      for (int j=0;j<HB;++j){
        int nt = h*HB+j;
        acc0[nt][0] = __builtin_amdgcn_mfma_f32_16x16x32_bf16(a0, bb[j], acc0[nt][0], 0,0,0);
        acc0[nt][1] = __builtin_amdgcn_mfma_f32_16x16x32_bf16(a1, bb[j], acc0[nt][1], 0,0,0);
      }
    }
  }
  // gate cols -> gls (conv1)
  if (CONV1){
#pragma unroll
    for (int nt=0; nt<NT0; ++nt){
      int colb = wcol0 + nt*16;
      if (colb >= 384){
        float bc = b0[colb + lrow];
#pragma unroll
        for (int mt=0; mt<2; ++mt)
#pragma unroll
        for (int r=0; r<4; ++r){
          int el = mt*16 + lhi*4 + r;
          gls[el*256 + colb + lrow - 384] = f2bf(silu_f(acc0[nt][mt][r] + bc));
        }
      }
    }
  }
  __syncthreads();                            // B2: A0 reads done, gls ready

  // ---- A1.half1 prefetch ----
  uint4 mz1b[4], rz1b[4];
#pragma unroll
  for (int i=0;i<4;++i){
    int ch = t + 256*i + 1024;                // rows 32..63
    int row = ch >> 5, k0 = (ch & 31) * 8;
    int e = e0 + (row >> 1);
    mz1b[i] = z4; rz1b[i] = z4;
    if (e < EDGES){
      mz1b[i] = *(const uint4*)(msg + (size_t)e*1152 + 384 + (row&1)*256 + k0);
      rz1b[i] = *(const uint4*)(rad + (size_t)e*768  + 384 + k0);
    }
  }

  // ---- y0 stage into ldsA as [32][392] bf16 (padded, 24.5KB) ----
  {
    bf16* y0 = (bf16*)ldsA;
#pragma unroll
    for (int nt=0; nt<NT0; ++nt){
      int colb = wcol0 + nt*16;
      if (colb < 384){
        int col = colb + lrow;
        int f = col >> 7, c = col & 127;
        float bc = b0[col];
#pragma unroll
        for (int mt=0; mt<2; ++mt)
#pragma unroll
        for (int r=0; r<4; ++r){
          int el = mt*16 + lhi*4 + r;
          float v = acc0[nt][mt][r] + bc;
          float o;
          if (CONV1) o = (f==0) ? silu_f(v) : v * bf2f(gls[el*256 + (f==2?128:0) + c]);
          else       o = v;
          y0[el*392 + col] = f2bf(o);
        }
      }
    }
  }
  __syncthreads();                            // B3: y0 staged
  // ---- coalesced store msg rows 0-2 ----
  {
    const bf16* y0 = (const bf16*)ldsA;
#pragma unroll
    for (int i=0;i<6;++i){
      int idx = t + 256*i;                    // 0..1535
      int el = idx / 48, rem = idx - el*48;
      if (el < evalid)
        *(uint4*)(msg + (size_t)(e0+el)*1152 + rem*8) = *(const uint4*)&y0[el*392 + rem*8];
    }
  }
  __syncthreads();                            // B4: y0 reads done

  // ---- A1 writes [64][512B-rows] swizzled ----
#pragma unroll
  for (int i=0;i<4;++i){
    int ch = t + 256*i;
    int row = ch >> 5, k0 = (ch & 31) * 8;
    *(uint4*)(ldsA + ((row*512 + k0*2) ^ ((row&7)<<4))) = mulp(mz1[i], rz1[i]);
  }
#pragma unroll
  for (int i=0;i<4;++i){
    int ch = t + 256*i + 1024;
    int row = ch >> 5, k0 = (ch & 31) * 8;
    *(uint4*)(ldsA + ((row*512 + k0*2) ^ ((row&7)<<4))) = mulp(mz1b[i], rz1b[i]);
  }

  // ---- A2 prefetch (in flight across G1) ----
  uint4 mz2[4], rz2[4];
#pragma unroll
  for (int i=0;i<4;++i){
    int ch = t + 256*i;                       // 0..1023
    int row = ch >> 4, k0 = (ch & 15) * 8;
    int e = e0 + (row >> 1);
    mz2[i] = z4; rz2[i] = z4;
    if (e < EDGES){
      mz2[i] = *(const uint4*)(msg + (size_t)e*1152 + 896 + (row&1)*128 + k0);
      rz2[i] = *(const uint4*)(rad + (size_t)e*768  + 640 + k0);
    }
  }
  __syncthreads();                            // B5: A1 ready

  // ---- G1: K=256, N=512; per half: B batched x8 ----
#pragma unroll
  for (int half=0; half<2; ++half){
    f32x4 acc1[4][2][2];
#pragma unroll
    for (int p=0;p<4;++p){ acc1[p][0][0]=zf; acc1[p][0][1]=zf; acc1[p][1][0]=zf; acc1[p][1][1]=zf; }
    for (int ks=0; ks<8; ++ks){
      bf16x8v aA[2];
#pragma unroll
      for (int m2=0; m2<2; ++m2){
        int row = (half*2+m2)*16 + lrow;
        aA[m2] = *(const bf16x8v*)(ldsA + ((row*512 + ks*64 + lhi*16) ^ ((row&7)<<4)));
      }
      bf16x8v br[4], bi[4];
#pragma unroll
      for (int p=0; p<4; ++p){
        int jj = wv*64 + p*16 + lrow;
        br[p] = *(const bf16x8v*)(w1t + (size_t)jj*256       + ks*32 + lhi*8);
        bi[p] = *(const bf16x8v*)(w1t + (size_t)(jj+256)*256 + ks*32 + lhi*8);
      }
#pragma unroll
      for (int p=0; p<4; ++p)
#pragma unroll
      for (int m2=0;m2<2;++m2){
        acc1[p][m2][0] = __builtin_amdgcn_mfma_f32_16x16x32_bf16(aA[m2], br[p], acc1[p][m2][0], 0,0,0);
        acc1[p][m2][1] = __builtin_amdgcn_mfma_f32_16x16x32_bf16(aA[m2], bi[p], acc1[p][m2][1], 0,0,0);
      }
    }
    __syncthreads();                          // A1(this half) reads done
    // stage y1 half: [16][512] bf16 at ldsA[0:16KB] (rows of other half live at 16-32KB)
    {
      bf16* y1 = (bf16*)ldsA;
#pragma unroll
      for (int p=0;p<4;++p)
#pragma unroll
      for (int m2=0;m2<2;++m2)
#pragma unroll
      for (int re=0;re<2;++re){
        int elL = m2*8 + lhi*2 + re;          // 0..15
        int el  = half*16 + elL;
        float r0 = acc1[p][m2][0][2*re+0], r1 = acc1[p][m2][0][2*re+1];
        float i0 = acc1[p][m2][1][2*re+0], i1 = acc1[p][m2][1][2*re+1];
        float o0 = r0 - i1, o1 = r1 + i0;
        int jj = wv*64 + p*16 + lrow;
        if (CONV1){ float g = bf2f(gls[el*256 + jj]); o0 *= g; o1 *= g; }
        y1[elL*512 + jj]       = f2bf(o0);
        y1[elL*512 + 256 + jj] = f2bf(o1);
      }
    }
    __syncthreads();                          // y1 half staged
    {
      const bf16* y1 = (const bf16*)ldsA;
#pragma unroll
      for (int i=0;i<4;++i){
        int idx = t + 256*i;                  // 0..1023
        int elL = idx >> 6, c0 = (idx & 63) * 8;
        int el = half*16 + elL;
        if (el < evalid)
          *(uint4*)(msg + (size_t)(e0+el)*1152 + 384 + c0) = *(const uint4*)&y1[elL*512 + c0];
      }
    }
    __syncthreads();                          // y1 half reads done (before overwrite / A2)
  }

  // ---- A2 writes [64][256B-rows] swizzled ----
#pragma unroll
  for (int i=0;i<4;++i){
    int ch = t + 256*i;
    int row = ch >> 4, k0 = (ch & 15) * 8;
    *(uint4*)(ldsA + ((row*256 + k0*2) ^ ((row&7)<<4))) = mulp(mz2[i], rz2[i]);
  }
  __syncthreads();                            // A2 ready

  // ---- G2: K=128, N=256; B batched x4 ----
  {
    f32x4 acc2[2][4][2];
#pragma unroll
    for (int p=0;p<2;++p)
#pragma unroll
    for (int mt=0;mt<4;++mt){ acc2[p][mt][0]=zf; acc2[p][mt][1]=zf; }
    for (int ks=0; ks<4; ++ks){
      bf16x8v aA[4];
#pragma unroll
      for (int mt=0;mt<4;++mt){
        int row = mt*16 + lrow;
        aA[mt] = *(const bf16x8v*)(ldsA + ((row*256 + ks*64 + lhi*16) ^ ((row&7)<<4)));
      }
      bf16x8v br2[2], bi2[2];
#pragma unroll
      for (int p=0;p<2;++p){
        int jj = wv*32 + p*16 + lrow;
        br2[p] = *(const bf16x8v*)(w2t + (size_t)jj*128       + ks*32 + lhi*8);
        bi2[p] = *(const bf16x8v*)(w2t + (size_t)(jj+128)*128 + ks*32 + lhi*8);
      }
#pragma unroll
      for (int p=0;p<2;++p)
#pragma unroll
      for (int mt=0;mt<4;++mt){
        acc2[p][mt][0] = __builtin_amdgcn_mfma_f32_16x16x32_bf16(aA[mt], br2[p], acc2[p][mt][0], 0,0,0);
        acc2[p][mt][1] = __builtin_amdgcn_mfma_f32_16x16x32_bf16(aA[mt], bi2[p], acc2[p][mt][1], 0,0,0);
      }
    }
    __syncthreads();                          // A2 reads done
    // stage y2: [32][264] bf16 (16.9KB, padded)
    {
      bf16* y2 = (bf16*)ldsA;
#pragma unroll
      for (int p=0;p<2;++p)
#pragma unroll
      for (int mt=0;mt<4;++mt)
#pragma unroll
      for (int re=0;re<2;++re){
        int el = mt*8 + lhi*2 + re;
        float r0 = acc2[p][mt][0][2*re+0], r1 = acc2[p][mt][0][2*re+1];
        float i0 = acc2[p][mt][1][2*re+0], i1 = acc2[p][mt][1][2*re+1];
        float o0 = r0 - i1, o1 = r1 + i0;
        int jj = wv*32 + p*16 + lrow;
        if (CONV1){ float g = bf2f(gls[el*256 + 128 + jj]); o0 *= g; o1 *= g; }
        y2[el*264 + jj]       = f2bf(o0);
        y2[el*264 + 128 + jj] = f2bf(o1);
      }
    }
    __syncthreads();                          // y2 staged
    {
      const bf16* y2 = (const bf16*)ldsA;
#pragma unroll
      for (int i=0;i<4;++i){
        int idx = t + 256*i;                  // 0..1023
        int el = idx >> 5, c0 = (idx & 31) * 8;
        if (el < evalid)
          *(uint4*)(msg + (size_t)(e0+el)*1152 + 896 + c0) = *(const uint4*)&y2[el*264 + c0];
      }
    }
  }
}

// ---------------------------------------------------------------------------
// K5: out[dst] += wigner_inv[e] @ msg[e]
// ---------------------------------------------------------------------------
__global__ __launch_bounds__(128)
void k_wiginv_scatter(const bf16* __restrict__ msg, const int* __restrict__ eidx,
                      const float* __restrict__ wiginv, float* __restrict__ out)
{
  const int e = blockIdx.x;
  const int c = threadIdx.x;
  __shared__ float wl[81];
  if (c < 81) wl[c] = wiginv[e*81 + c];
  float m[9];
#pragma unroll
  for (int r=0;r<9;++r) m[r] = bf2f(msg[(size_t)e*1152 + r*128 + c]);
  const int dst = eidx[EDGES + e];
  __syncthreads();
  float* op = out + (size_t)dst*1152 + c;
#pragma unroll
  for (int f=0;f<9;++f){
    float a = 0.f;
#pragma unroll
    for (int r=0;r<9;++r) a = fmaf(wl[f*9+r], m[r], a);
    atomicAdd(op + f*128, a);
  }
}

// ---------------------------------------------------------------------------
extern "C" void kernel_launch(void* const* d_in, const int* in_sizes, int n_in,
                              void* d_out, int out_size, void* d_ws, size_t ws_size,
                              hipStream_t stream)
{
  const float* x       = (const float*)d_in[0];
  const float* x_edge  = (const float*)d_in[1];
  const int*   eidx    = (const int*)  d_in[3];
  const float* wig     = (const float*)d_in[4];
  const float* wiginv  = (const float*)d_in[5];
  const float* r1w1    = (const float*)d_in[6];
  const float* r1b1    = (const float*)d_in[7];
  const float* r1g     = (const float*)d_in[8];
  const float* r1bt    = (const float*)d_in[9];
  const float* r1w2    = (const float*)d_in[10];
  const float* r1b2    = (const float*)d_in[11];
  const float* c1w0    = (const float*)d_in[12];
  const float* c1b0    = (const float*)d_in[13];
  const float* c1w1    = (const float*)d_in[14];
  const float* c1w2    = (const float*)d_in[15];
  const float* r2w1    = (const float*)d_in[16];
  const float* r2b1    = (const float*)d_in[17];
  const float* r2g     = (const float*)d_in[18];
  const float* r2bt    = (const float*)d_in[19];
  const float* r2w2    = (const float*)d_in[20];
  const float* r2b2    = (const float*)d_in[21];
  const float* c2w0    = (const float*)d_in[22];
  const float* c2b0    = (const float*)d_in[23];
  const float* c2w1    = (const float*)d_in[24];
  const float* c2w2    = (const float*)d_in[25];
  float* out = (float*)d_out;

  // ws layout: msg 115.2MB | rad 76.8MB | bf16 [N][K] weights ~1.44MB
  char* ws = (char*)d_ws;
  bf16* msg  = (bf16*)(ws);
  bf16* rad  = (bf16*)(ws + (size_t)115200000);
  bf16* w0t1 = (bf16*)(ws + (size_t)192000000);   // 640x384
  bf16* w1t1 = (bf16*)(ws + (size_t)192491520);   // 512x256
  bf16* w2t1 = (bf16*)(ws + (size_t)192753664);   // 256x128
  bf16* w0t2 = (bf16*)(ws + (size_t)192819200);   // 384x384
  bf16* w1t2 = (bf16*)(ws + (size_t)193114112);   // 512x256
  bf16* w2t2 = (bf16*)(ws + (size_t)193376256);   // 256x128

  k_wT<<<dim3(12,20),256,0,stream>>>(c1w0, w0t1, 384, 640);
  k_wT<<<dim3( 8,16),256,0,stream>>>(c1w1, w1t1, 256, 512);
  k_wT<<<dim3( 4, 8),256,0,stream>>>(c1w2, w2t1, 128, 256);
  k_wT<<<dim3(12,12),256,0,stream>>>(c2w0, w0t2, 384, 384);
  k_wT<<<dim3( 8,16),256,0,stream>>>(c2w1, w1t2, 256, 512);
  k_wT<<<dim3( 4, 8),256,0,stream>>>(c2w2, w2t2, 128, 256);

  hipMemsetAsync(d_out, 0, (size_t)out_size*sizeof(float), stream);
  k_gather_rot<<<EDGES, 128, 0, stream>>>(x, eidx, wig, msg);
  k_radial<<<EDGES/16, 256, 0, stream>>>(x_edge, r1w1, r1b1, r1g, r1bt, r1w2, r1b2, rad);
  k_so2_mfma<true ><<<(EDGES+31)/32, 256, 0, stream>>>(rad, w0t1, c1b0, w1t1, w2t1, msg);
  k_radial<<<EDGES/16, 256, 0, stream>>>(x_edge, r2w1, r2b1, r2g, r2bt, r2w2, r2b2, rad);
  k_so2_mfma<false><<<(EDGES+31)/32, 256, 0, stream>>>(rad, w0t2, c2b0, w1t2, w2t2, msg);
  k_wiginv_scatter<<<EDGES, 128, 0, stream>>>(msg, eidx, wiginv, out);
}

// Round 12
// 1415.869 us; speedup vs baseline: 1.0411x; 1.0317x over previous
//
#include <hip/hip_runtime.h>
#include <hip/hip_bf16.h>

#define EDGES 50000
#define NODES 10000

typedef __hip_bfloat16 bf16;
typedef __attribute__((ext_vector_type(8))) short bf16x8v;  // 8 bf16 = 4 VGPR (MFMA A/B frag)
typedef __attribute__((ext_vector_type(4))) float f32x4;    // MFMA C/D frag

__device__ __forceinline__ float bf2f(bf16 v){ return __bfloat162float(v); }
__device__ __forceinline__ bf16  f2bf(float v){ return __float2bfloat16(v); }
__device__ __forceinline__ unsigned short f2bfu(float f){
  bf16 h = __float2bfloat16(f);
  union{ bf16 h; unsigned short s; } u; u.h = h; return u.s;
}
__device__ __forceinline__ float silu_f(float v){ return v * (1.0f/(1.0f+__expf(-v))); }

// packed bf16x2 multiply (staging: xs = msg * rad)
__device__ __forceinline__ unsigned mul1(unsigned a, unsigned b){
  union{unsigned u; float f;} a0,a1,b0,b1;
  a0.u = (a & 0xffffu) << 16; a1.u = a & 0xffff0000u;
  b0.u = (b & 0xffffu) << 16; b1.u = b & 0xffff0000u;
  float p0 = a0.f*b0.f, p1 = a1.f*b1.f;
  return (unsigned)f2bfu(p0) | ((unsigned)f2bfu(p1) << 16);
}
__device__ __forceinline__ uint4 mulp(uint4 a, uint4 b){
  uint4 r; r.x=mul1(a.x,b.x); r.y=mul1(a.y,b.y); r.z=mul1(a.z,b.z); r.w=mul1(a.w,b.w); return r;
}

// ---------------------------------------------------------------------------
// K0: weight prep — w[K][N] f32  ->  wt[N][K] bf16
// ---------------------------------------------------------------------------
__global__ __launch_bounds__(256)
void k_wT(const float* __restrict__ w, bf16* __restrict__ wt, int K, int N){
  __shared__ float tile[32][33];
  const int kb = blockIdx.x*32, nb = blockIdx.y*32;
  const int tx = threadIdx.x & 31, ty = threadIdx.x >> 5;   // 32 x 8
#pragma unroll
  for (int i=0;i<32;i+=8) tile[ty+i][tx] = w[(size_t)(kb+ty+i)*N + nb+tx];
  __syncthreads();
#pragma unroll
  for (int i=0;i<32;i+=8) wt[(size_t)(nb+ty+i)*K + kb+tx] = f2bf(tile[tx][ty+i]);
}

// ---------------------------------------------------------------------------
// K1: msg[e] = wigner[e] @ x[src[e]]
// ---------------------------------------------------------------------------
__global__ __launch_bounds__(128)
void k_gather_rot(const float* __restrict__ x, const int* __restrict__ eidx,
                  const float* __restrict__ wig, bf16* __restrict__ msg)
{
  const int e = blockIdx.x;
  const int c = threadIdx.x;
  __shared__ float wl[81];
  if (c < 81) wl[c] = wig[e*81 + c];
  const int src = eidx[e];
  const float* xp = x + (size_t)src*1152 + c;
  float xr[9];
#pragma unroll
  for (int f=0; f<9; ++f) xr[f] = xp[f*128];
  __syncthreads();
  bf16* mp = msg + (size_t)e*1152 + c;
#pragma unroll
  for (int fo=0; fo<9; ++fo){
    float a = 0.f;
#pragma unroll
    for (int f=0; f<9; ++f) a = fmaf(wl[fo*9+f], xr[f], a);
    mp[fo*128] = f2bf(a);
  }
}

// ---------------------------------------------------------------------------
// K2: rad[e] = silu(LN(x_edge@w1+b1))@w2 + b2
// ---------------------------------------------------------------------------
__global__ __launch_bounds__(256)
void k_radial(const float* __restrict__ x_edge,
              const float* __restrict__ w1, const float* __restrict__ b1,
              const float* __restrict__ gm, const float* __restrict__ bt,
              const float* __restrict__ w2, const float* __restrict__ b2,
              bf16* __restrict__ ro)
{
  __shared__ float xe[16][128];
  __shared__ float h[16][128];
  __shared__ float mu_s[16], rs_s[16];
  const int t = threadIdx.x;
  const int e0 = blockIdx.x * 16;
  for (int i=0;i<8;++i){
    int lin = t + 256*i;
    int e = lin >> 7, j2 = lin & 127;
    xe[e][j2] = x_edge[(size_t)(e0+e)*128 + j2];
  }
  __syncthreads();
  const int j = t & 127, g = t >> 7;
  {
    float acc[8] = {0,0,0,0,0,0,0,0};
    for (int k=0;k<128;k+=4){
      float wv0 = w1[(k+0)*128+j];
      float wv1 = w1[(k+1)*128+j];
      float wv2 = w1[(k+2)*128+j];
      float wv3 = w1[(k+3)*128+j];
#pragma unroll
      for (int e=0;e<8;++e){
        float4 xv = *(const float4*)&xe[g*8+e][k];
        acc[e] += xv.x*wv0 + xv.y*wv1 + xv.z*wv2 + xv.w*wv3;
      }
    }
    float bv = b1[j];
#pragma unroll
    for (int e=0;e<8;++e) h[g*8+e][j] = acc[e] + bv;
  }
  __syncthreads();
  {
    int e = t >> 4, p = t & 15;
    float s=0.f, ss=0.f;
#pragma unroll
    for (int i=0;i<8;++i){ float v = h[e][p+16*i]; s += v; ss += v*v; }
#pragma unroll
    for (int off=8; off>0; off>>=1){ s += __shfl_xor(s, off, 16); ss += __shfl_xor(ss, off, 16); }
    if (p==0){
      float m = s*(1.f/128.f);
      mu_s[e] = m;
      rs_s[e] = rsqrtf(fmaxf(ss*(1.f/128.f)-m*m, 0.f) + 1e-5f);
    }
  }
  __syncthreads();
  {
    float gv = gm[j], bv = bt[j];
#pragma unroll
    for (int e=0;e<8;++e){
      int ee = g*8+e;
      float v = (h[ee][j]-mu_s[ee])*rs_s[ee]*gv + bv;
      h[ee][j] = silu_f(v);
    }
  }
  __syncthreads();
  if (t < 192){
    int col = t*4;
    float acc[16][4];
#pragma unroll
    for (int e=0;e<16;++e){ acc[e][0]=acc[e][1]=acc[e][2]=acc[e][3]=0.f; }
    for (int k=0;k<128;k+=4){
      float4 wv0 = *(const float4*)&w2[(k+0)*768+col];
      float4 wv1 = *(const float4*)&w2[(k+1)*768+col];
      float4 wv2 = *(const float4*)&w2[(k+2)*768+col];
      float4 wv3 = *(const float4*)&w2[(k+3)*768+col];
#pragma unroll
      for (int e=0;e<16;++e){
        float4 hv = *(const float4*)&h[e][k];
        acc[e][0] += hv.x*wv0.x + hv.y*wv1.x + hv.z*wv2.x + hv.w*wv3.x;
        acc[e][1] += hv.x*wv0.y + hv.y*wv1.y + hv.z*wv2.y + hv.w*wv3.y;
        acc[e][2] += hv.x*wv0.z + hv.y*wv1.z + hv.z*wv2.z + hv.w*wv3.z;
        acc[e][3] += hv.x*wv0.w + hv.y*wv1.w + hv.z*wv2.w + hv.w*wv3.w;
      }
    }
    float4 bv = *(const float4*)&b2[col];
#pragma unroll
    for (int e=0;e<16;++e){
      ushort4 pk;
      pk.x = f2bfu(acc[e][0]+bv.x);
      pk.y = f2bfu(acc[e][1]+bv.y);
      pk.z = f2bfu(acc[e][2]+bv.z);
      pk.w = f2bfu(acc[e][3]+bv.w);
      *reinterpret_cast<ushort4*>(&ro[(size_t)(e0+e)*768 + col]) = pk;
    }
  }
}

// ---------------------------------------------------------------------------
// SO2 conv split into 3 streaming GEMM kernels (round-9 pivot: the fused
// 10-phase/block chain was latency-bound at 5% MfmaUtil; homogeneous short
// kernels restore wave-level latency hiding). Math identical to fused ver.
// ---------------------------------------------------------------------------

// G0: [32e x 384] @ w0t -> N0 cols; conv1 writes gate (silu'd) to glb.
template<bool CONV1>
__global__ __launch_bounds__(256, 3)
void k_g0(const bf16* __restrict__ rad, const bf16* __restrict__ msg_in,
          const bf16* __restrict__ w0t, const float* __restrict__ b0,
          bf16* __restrict__ msg, bf16* __restrict__ glb)
{
  __shared__ char ldsA[24576];        // [32][768B] swizzled
  __shared__ bf16 gls[8192];          // [32][256] gate (conv1)
  const int t = threadIdx.x;
  const int lane = t & 63, wv = t >> 6;
  const int lrow = lane & 15, lhi = lane >> 4;
  const int e0 = blockIdx.x * 32;
  int evalid = EDGES - e0; if (evalid > 32) evalid = 32;
  const uint4 z4 = {0u,0u,0u,0u};
  const f32x4 zf = {0.f,0.f,0.f,0.f};

  // stage A0
#pragma unroll
  for (int i=0;i<6;++i){
    int ch = t + 256*i;                       // 0..1535
    int row = ch / 48, k0 = (ch % 48) * 8;
    int e = e0 + row;
    uint4 mz = z4, rz = z4;
    if (e < EDGES){
      mz = *(const uint4*)(msg_in + (size_t)e*1152 + k0);
      rz = *(const uint4*)(rad    + (size_t)e*768  + k0);
    }
    *(uint4*)(ldsA + ((row*768 + k0*2) ^ ((row&7)<<4))) = mulp(mz, rz);
  }
  __syncthreads();

  constexpr int NT0 = CONV1 ? 10 : 6;
  constexpr int HB  = NT0 / 2;
  const int wcol0 = wv * NT0 * 16;
  f32x4 acc0[NT0][2];
#pragma unroll
  for (int nt=0; nt<NT0; ++nt){ acc0[nt][0]=zf; acc0[nt][1]=zf; }
  for (int ks=0; ks<12; ++ks){
    bf16x8v a0 = *(const bf16x8v*)(ldsA + (((lrow   )*768 + ks*64 + lhi*16) ^ ((lrow&7)<<4)));
    bf16x8v a1 = *(const bf16x8v*)(ldsA + (((16+lrow)*768 + ks*64 + lhi*16) ^ ((lrow&7)<<4)));
#pragma unroll
    for (int h=0; h<2; ++h){
      bf16x8v bb[HB];
#pragma unroll
      for (int j=0;j<HB;++j){
        int coln = wcol0 + (h*HB+j)*16 + lrow;
        bb[j] = *(const bf16x8v*)(w0t + (size_t)coln*384 + ks*32 + lhi*8);
      }
#pragma unroll
      for (int j=0;j<HB;++j){
        int nt = h*HB+j;
        acc0[nt][0] = __builtin_amdgcn_mfma_f32_16x16x32_bf16(a0, bb[j], acc0[nt][0], 0,0,0);
        acc0[nt][1] = __builtin_amdgcn_mfma_f32_16x16x32_bf16(a1, bb[j], acc0[nt][1], 0,0,0);
      }
    }
  }
  if (CONV1){
#pragma unroll
    for (int nt=0; nt<NT0; ++nt){
      int colb = wcol0 + nt*16;
      if (colb >= 384){
        float bc = b0[colb + lrow];
        int cc = colb + lrow - 384;
#pragma unroll
        for (int mt=0; mt<2; ++mt)
#pragma unroll
        for (int r=0; r<4; ++r){
          int el = mt*16 + lhi*4 + r;
          bf16 gv = f2bf(silu_f(acc0[nt][mt][r] + bc));
          gls[el*256 + cc] = gv;
          if (el < evalid) glb[(size_t)(e0+el)*256 + cc] = gv;
        }
      }
    }
    __syncthreads();                          // gls ready
  }
  // out0 epilogue (rows 0-2)
#pragma unroll
  for (int nt=0; nt<NT0; ++nt){
    int colb = wcol0 + nt*16;
    if (colb < 384){
      int col = colb + lrow;
      int f = col >> 7, c = col & 127;
      float bc = b0[col];
#pragma unroll
      for (int mt=0; mt<2; ++mt)
#pragma unroll
      for (int r=0; r<4; ++r){
        int el = mt*16 + lhi*4 + r;
        if (el < evalid){
          float v = acc0[nt][mt][r] + bc;
          float o;
          if (CONV1) o = (f==0) ? silu_f(v) : v * bf2f(gls[el*256 + (f==2?128:0) + c]);
          else       o = v;
          msg[(size_t)(e0+el)*1152 + col] = f2bf(o);
        }
      }
    }
  }
}

// G1: 16 edges/block, A[32x256] @ w1t -> 512; r/i recombine; gate from glb.
template<bool CONV1>
__global__ __launch_bounds__(256, 3)
void k_g1(const bf16* __restrict__ rad,
          const bf16* __restrict__ w1t,
          bf16* __restrict__ msg, const bf16* __restrict__ glb)
{
  __shared__ char ldsA[16384];        // [32][512B] swizzled
  const int t = threadIdx.x;
  const int lane = t & 63, wv = t >> 6;
  const int lrow = lane & 15, lhi = lane >> 4;
  const int e0 = blockIdx.x * 16;
  const uint4 z4 = {0u,0u,0u,0u};
  const f32x4 zf = {0.f,0.f,0.f,0.f};

  // stage: rows = 2*eL + m
#pragma unroll
  for (int i=0;i<4;++i){
    int ch = t + 256*i;                       // 0..1023
    int row = ch >> 5, k0 = (ch & 31) * 8;
    int e = e0 + (row >> 1);
    uint4 mz = z4, rz = z4;
    if (e < EDGES){
      mz = *(const uint4*)(msg + (size_t)e*1152 + 384 + (row&1)*256 + k0);
      rz = *(const uint4*)(rad + (size_t)e*768  + 384 + k0);
    }
    *(uint4*)(ldsA + ((row*512 + k0*2) ^ ((row&7)<<4))) = mulp(mz, rz);
  }
  __syncthreads();

  f32x4 acc1[4][2][2];
#pragma unroll
  for (int p=0;p<4;++p){ acc1[p][0][0]=zf; acc1[p][0][1]=zf; acc1[p][1][0]=zf; acc1[p][1][1]=zf; }
  for (int ks=0; ks<8; ++ks){
    bf16x8v aA[2];
#pragma unroll
    for (int m2=0; m2<2; ++m2){
      int row = m2*16 + lrow;
      aA[m2] = *(const bf16x8v*)(ldsA + ((row*512 + ks*64 + lhi*16) ^ ((row&7)<<4)));
    }
    bf16x8v br[4], bi[4];
#pragma unroll
    for (int p=0; p<4; ++p){
      int jj = wv*64 + p*16 + lrow;
      br[p] = *(const bf16x8v*)(w1t + (size_t)jj*256       + ks*32 + lhi*8);
      bi[p] = *(const bf16x8v*)(w1t + (size_t)(jj+256)*256 + ks*32 + lhi*8);
    }
#pragma unroll
    for (int p=0; p<4; ++p)
#pragma unroll
    for (int m2=0;m2<2;++m2){
      acc1[p][m2][0] = __builtin_amdgcn_mfma_f32_16x16x32_bf16(aA[m2], br[p], acc1[p][m2][0], 0,0,0);
      acc1[p][m2][1] = __builtin_amdgcn_mfma_f32_16x16x32_bf16(aA[m2], bi[p], acc1[p][m2][1], 0,0,0);
    }
  }
  // epilogue rows 3-6
#pragma unroll
  for (int p=0;p<4;++p)
#pragma unroll
  for (int m2=0;m2<2;++m2)
#pragma unroll
  for (int re=0;re<2;++re){
    int elL = m2*8 + lhi*2 + re;              // 0..15
    int e = e0 + elL;
    if (e < EDGES){
      float r0 = acc1[p][m2][0][2*re+0], r1 = acc1[p][m2][0][2*re+1];
      float i0 = acc1[p][m2][1][2*re+0], i1 = acc1[p][m2][1][2*re+1];
      float o0 = r0 - i1, o1 = r1 + i0;
      int jj = wv*64 + p*16 + lrow;
      if (CONV1){ float g = bf2f(glb[(size_t)e*256 + jj]); o0 *= g; o1 *= g; }
      size_t base = (size_t)e*1152;
      msg[base + 384 + jj] = f2bf(o0);
      msg[base + 640 + jj] = f2bf(o1);
    }
  }
}

// G2: 32 edges/block, A[64x128] @ w2t -> 256; r/i recombine; gate from glb.
template<bool CONV1>
__global__ __launch_bounds__(256, 3)
void k_g2(const bf16* __restrict__ rad,
          const bf16* __restrict__ w2t,
          bf16* __restrict__ msg, const bf16* __restrict__ glb)
{
  __shared__ char ldsA[16384];        // [64][256B] swizzled
  const int t = threadIdx.x;
  const int lane = t & 63, wv = t >> 6;
  const int lrow = lane & 15, lhi = lane >> 4;
  const int e0 = blockIdx.x * 32;
  const uint4 z4 = {0u,0u,0u,0u};
  const f32x4 zf = {0.f,0.f,0.f,0.f};

#pragma unroll
  for (int i=0;i<4;++i){
    int ch = t + 256*i;                       // 0..1023
    int row = ch >> 4, k0 = (ch & 15) * 8;
    int e = e0 + (row >> 1);
    uint4 mz = z4, rz = z4;
    if (e < EDGES){
      mz = *(const uint4*)(msg + (size_t)e*1152 + 896 + (row&1)*128 + k0);
      rz = *(const uint4*)(rad + (size_t)e*768  + 640 + k0);
    }
    *(uint4*)(ldsA + ((row*256 + k0*2) ^ ((row&7)<<4))) = mulp(mz, rz);
  }
  __syncthreads();

  f32x4 acc2[2][4][2];
#pragma unroll
  for (int p=0;p<2;++p)
#pragma unroll
  for (int mt=0;mt<4;++mt){ acc2[p][mt][0]=zf; acc2[p][mt][1]=zf; }
  for (int ks=0; ks<4; ++ks){
    bf16x8v aA[4];
#pragma unroll
    for (int mt=0;mt<4;++mt){
      int row = mt*16 + lrow;
      aA[mt] = *(const bf16x8v*)(ldsA + ((row*256 + ks*64 + lhi*16) ^ ((row&7)<<4)));
    }
    bf16x8v br2[2], bi2[2];
#pragma unroll
    for (int p=0;p<2;++p){
      int jj = wv*32 + p*16 + lrow;
      br2[p] = *(const bf16x8v*)(w2t + (size_t)jj*128       + ks*32 + lhi*8);
      bi2[p] = *(const bf16x8v*)(w2t + (size_t)(jj+128)*128 + ks*32 + lhi*8);
    }
#pragma unroll
    for (int p=0;p<2;++p)
#pragma unroll
    for (int mt=0;mt<4;++mt){
      acc2[p][mt][0] = __builtin_amdgcn_mfma_f32_16x16x32_bf16(aA[mt], br2[p], acc2[p][mt][0], 0,0,0);
      acc2[p][mt][1] = __builtin_amdgcn_mfma_f32_16x16x32_bf16(aA[mt], bi2[p], acc2[p][mt][1], 0,0,0);
    }
  }
  // epilogue rows 7,8
#pragma unroll
  for (int p=0;p<2;++p)
#pragma unroll
  for (int mt=0;mt<4;++mt)
#pragma unroll
  for (int re=0;re<2;++re){
    int el = mt*8 + lhi*2 + re;               // 0..31
    int e = e0 + el;
    if (e < EDGES){
      float r0 = acc2[p][mt][0][2*re+0], r1 = acc2[p][mt][0][2*re+1];
      float i0 = acc2[p][mt][1][2*re+0], i1 = acc2[p][mt][1][2*re+1];
      float o0 = r0 - i1, o1 = r1 + i0;
      int jj = wv*32 + p*16 + lrow;
      if (CONV1){ float g = bf2f(glb[(size_t)e*256 + 128 + jj]); o0 *= g; o1 *= g; }
      size_t base = (size_t)e*1152;
      msg[base + 896  + jj] = f2bf(o0);
      msg[base + 1024 + jj] = f2bf(o1);
    }
  }
}

// ---------------------------------------------------------------------------
// K5: out[dst] += wigner_inv[e] @ msg[e]
// ---------------------------------------------------------------------------
__global__ __launch_bounds__(128)
void k_wiginv_scatter(const bf16* __restrict__ msg, const int* __restrict__ eidx,
                      const float* __restrict__ wiginv, float* __restrict__ out)
{
  const int e = blockIdx.x;
  const int c = threadIdx.x;
  __shared__ float wl[81];
  if (c < 81) wl[c] = wiginv[e*81 + c];
  float m[9];
#pragma unroll
  for (int r=0;r<9;++r) m[r] = bf2f(msg[(size_t)e*1152 + r*128 + c]);
  const int dst = eidx[EDGES + e];
  __syncthreads();
  float* op = out + (size_t)dst*1152 + c;
#pragma unroll
  for (int f=0;f<9;++f){
    float a = 0.f;
#pragma unroll
    for (int r=0;r<9;++r) a = fmaf(wl[f*9+r], m[r], a);
    atomicAdd(op + f*128, a);
  }
}

// ---------------------------------------------------------------------------
extern "C" void kernel_launch(void* const* d_in, const int* in_sizes, int n_in,
                              void* d_out, int out_size, void* d_ws, size_t ws_size,
                              hipStream_t stream)
{
  const float* x       = (const float*)d_in[0];
  const float* x_edge  = (const float*)d_in[1];
  const int*   eidx    = (const int*)  d_in[3];
  const float* wig     = (const float*)d_in[4];
  const float* wiginv  = (const float*)d_in[5];
  const float* r1w1    = (const float*)d_in[6];
  const float* r1b1    = (const float*)d_in[7];
  const float* r1g     = (const float*)d_in[8];
  const float* r1bt    = (const float*)d_in[9];
  const float* r1w2    = (const float*)d_in[10];
  const float* r1b2    = (const float*)d_in[11];
  const float* c1w0    = (const float*)d_in[12];
  const float* c1b0    = (const float*)d_in[13];
  const float* c1w1    = (const float*)d_in[14];
  const float* c1w2    = (const float*)d_in[15];
  const float* r2w1    = (const float*)d_in[16];
  const float* r2b1    = (const float*)d_in[17];
  const float* r2g     = (const float*)d_in[18];
  const float* r2bt    = (const float*)d_in[19];
  const float* r2w2    = (const float*)d_in[20];
  const float* r2b2    = (const float*)d_in[21];
  const float* c2w0    = (const float*)d_in[22];
  const float* c2b0    = (const float*)d_in[23];
  const float* c2w1    = (const float*)d_in[24];
  const float* c2w2    = (const float*)d_in[25];
  float* out = (float*)d_out;

  // ws: msg 115.2MB | rad 76.8MB | bf16 weights ~1.44MB | glb 25.6MB  (~219MB)
  char* ws = (char*)d_ws;
  bf16* msg  = (bf16*)(ws);
  bf16* rad  = (bf16*)(ws + (size_t)115200000);
  bf16* w0t1 = (bf16*)(ws + (size_t)192000000);   // 640x384
  bf16* w1t1 = (bf16*)(ws + (size_t)192491520);   // 512x256
  bf16* w2t1 = (bf16*)(ws + (size_t)192753664);   // 256x128
  bf16* w0t2 = (bf16*)(ws + (size_t)192819200);   // 384x384
  bf16* w1t2 = (bf16*)(ws + (size_t)193114112);   // 512x256
  bf16* w2t2 = (bf16*)(ws + (size_t)193376256);   // 256x128
  bf16* glb  = (bf16*)(ws + (size_t)193441792);   // 50000x256 = 25.6MB

  k_wT<<<dim3(12,20),256,0,stream>>>(c1w0, w0t1, 384, 640);
  k_wT<<<dim3( 8,16),256,0,stream>>>(c1w1, w1t1, 256, 512);
  k_wT<<<dim3( 4, 8),256,0,stream>>>(c1w2, w2t1, 128, 256);
  k_wT<<<dim3(12,12),256,0,stream>>>(c2w0, w0t2, 384, 384);
  k_wT<<<dim3( 8,16),256,0,stream>>>(c2w1, w1t2, 256, 512);
  k_wT<<<dim3( 4, 8),256,0,stream>>>(c2w2, w2t2, 128, 256);

  hipMemsetAsync(d_out, 0, (size_t)out_size*sizeof(float), stream);
  k_gather_rot<<<EDGES, 128, 0, stream>>>(x, eidx, wig, msg);

  k_radial<<<EDGES/16, 256, 0, stream>>>(x_edge, r1w1, r1b1, r1g, r1bt, r1w2, r1b2, rad);
  k_g0<true ><<<(EDGES+31)/32, 256, 0, stream>>>(rad, msg, w0t1, c1b0, msg, glb);
  k_g1<true ><<<(EDGES+15)/16, 256, 0, stream>>>(rad, w1t1, msg, glb);
  k_g2<true ><<<(EDGES+31)/32, 256, 0, stream>>>(rad, w2t1, msg, glb);

  k_radial<<<EDGES/16, 256, 0, stream>>>(x_edge, r2w1, r2b1, r2g, r2bt, r2w2, r2b2, rad);
  k_g0<false><<<(EDGES+31)/32, 256, 0, stream>>>(rad, msg, w0t2, c2b0, msg, glb);
  k_g1<false><<<(EDGES+15)/16, 256, 0, stream>>>(rad, w1t2, msg, glb);
  k_g2<false><<<(EDGES+31)/32, 256, 0, stream>>>(rad, w2t2, msg, glb);

  k_wiginv_scatter<<<EDGES, 128, 0, stream>>>(msg, eidx, wiginv, out);
}

// Round 14
// 1222.231 us; speedup vs baseline: 1.2061x; 1.1584x over previous
//
#include <hip/hip_runtime.h>
#include <hip/hip_bf16.h>

#define EDGES 50000
#define NODES 10000

typedef __hip_bfloat16 bf16;
typedef __attribute__((ext_vector_type(8))) short bf16x8v;  // 8 bf16 = 4 VGPR (MFMA A/B frag)
typedef __attribute__((ext_vector_type(4))) float f32x4;    // MFMA C/D frag

__device__ __forceinline__ float bf2f(bf16 v){ return __bfloat162float(v); }
__device__ __forceinline__ bf16  f2bf(float v){ return __float2bfloat16(v); }
__device__ __forceinline__ unsigned short f2bfu(float f){
  bf16 h = __float2bfloat16(f);
  union{ bf16 h; unsigned short s; } u; u.h = h; return u.s;
}
__device__ __forceinline__ unsigned packbf2(float a, float b){
  return (unsigned)f2bfu(a) | ((unsigned)f2bfu(b) << 16);
}
__device__ __forceinline__ float silu_f(float v){ return v * (1.0f/(1.0f+__expf(-v))); }

// packed bf16x2 multiply (staging: xs = msg * rad)
__device__ __forceinline__ unsigned mul1(unsigned a, unsigned b){
  union{unsigned u; float f;} a0,a1,b0,b1;
  a0.u = (a & 0xffffu) << 16; a1.u = a & 0xffff0000u;
  b0.u = (b & 0xffffu) << 16; b1.u = b & 0xffff0000u;
  float p0 = a0.f*b0.f, p1 = a1.f*b1.f;
  return (unsigned)f2bfu(p0) | ((unsigned)f2bfu(p1) << 16);
}
__device__ __forceinline__ uint4 mulp(uint4 a, uint4 b){
  uint4 r; r.x=mul1(a.x,b.x); r.y=mul1(a.y,b.y); r.z=mul1(a.z,b.z); r.w=mul1(a.w,b.w); return r;
}

// ---------------------------------------------------------------------------
// K0: weight prep — w[K][N] f32  ->  wt[N][K] bf16
// ---------------------------------------------------------------------------
__global__ __launch_bounds__(256)
void k_wT(const float* __restrict__ w, bf16* __restrict__ wt, int K, int N){
  __shared__ float tile[32][33];
  const int kb = blockIdx.x*32, nb = blockIdx.y*32;
  const int tx = threadIdx.x & 31, ty = threadIdx.x >> 5;   // 32 x 8
#pragma unroll
  for (int i=0;i<32;i+=8) tile[ty+i][tx] = w[(size_t)(kb+ty+i)*N + nb+tx];
  __syncthreads();
#pragma unroll
  for (int i=0;i<32;i+=8) wt[(size_t)(nb+ty+i)*K + kb+tx] = f2bf(tile[tx][ty+i]);
}

// ---------------------------------------------------------------------------
// K1: msg[e] = wigner[e] @ x[src[e]]
// ---------------------------------------------------------------------------
__global__ __launch_bounds__(128)
void k_gather_rot(const float* __restrict__ x, const int* __restrict__ eidx,
                  const float* __restrict__ wig, bf16* __restrict__ msg)
{
  const int e = blockIdx.x;
  const int c = threadIdx.x;
  __shared__ float wl[81];
  if (c < 81) wl[c] = wig[e*81 + c];
  const int src = eidx[e];
  const float* xp = x + (size_t)src*1152 + c;
  float xr[9];
#pragma unroll
  for (int f=0; f<9; ++f) xr[f] = xp[f*128];
  __syncthreads();
  bf16* mp = msg + (size_t)e*1152 + c;
#pragma unroll
  for (int fo=0; fo<9; ++fo){
    float a = 0.f;
#pragma unroll
    for (int f=0; f<9; ++f) a = fmaf(wl[fo*9+f], xr[f], a);
    mp[fo*128] = f2bf(a);
  }
}

// ---------------------------------------------------------------------------
// K2: radial MLP via MFMA. 64 edges/block, 4 waves.
//   GEMM1: [64x128] @ w1t -> 128 (wave owns 16 rows, computes all 128 cols)
//   LN in-fragment: row cols live across 16 lrow-lanes -> shfl_xor width-16
//   silu -> h overwrites A-tile rows in LDS (wave-exclusive, no race)
//   GEMM2: [64x128] @ w2t -> 768 (3 n-chunks of 64 cols/wave)
// Round-12 PMC: old f32 k_radial = 228us, VALUBusy 66%, MfmaUtil 0.
// ---------------------------------------------------------------------------
__global__ __launch_bounds__(256, 3)
void k_radial_mfma(const float* __restrict__ x_edge,
                   const bf16* __restrict__ w1t, const float* __restrict__ b1,
                   const float* __restrict__ gm, const float* __restrict__ bt,
                   const bf16* __restrict__ w2t, const float* __restrict__ b2,
                   bf16* __restrict__ ro)
{
  __shared__ char ldsA[16384];        // [64][256B] bf16, swizzled; A then h in-place
  __shared__ float lb1[128], lg[128], lbt[128];
  const int t = threadIdx.x;
  const int lane = t & 63, wv = t >> 6;
  const int lrow = lane & 15, lhi = lane >> 4;
  const int e0 = blockIdx.x * 64;
  int evalid = EDGES - e0; if (evalid > 64) evalid = 64;
  const f32x4 zf = {0.f,0.f,0.f,0.f};

  if (t < 128){ lb1[t] = b1[t]; lg[t] = gm[t]; lbt[t] = bt[t]; }
  // stage x_edge -> bf16 LDS [64][128], swizzled
#pragma unroll
  for (int i=0;i<2;++i){
    int ch = t + 256*i;                       // 0..511
    int row = ch >> 3, k0 = (ch & 7) * 16;
    int e = e0 + row;
    uint4 o = {0u,0u,0u,0u};
    uint4 o2 = {0u,0u,0u,0u};
    if (e < EDGES){
      const float* xp = x_edge + (size_t)e*128 + k0;
      float4 a0 = *(const float4*)(xp+0), a1 = *(const float4*)(xp+4);
      float4 a2 = *(const float4*)(xp+8), a3 = *(const float4*)(xp+12);
      o.x  = packbf2(a0.x,a0.y); o.y  = packbf2(a0.z,a0.w);
      o.z  = packbf2(a1.x,a1.y); o.w  = packbf2(a1.z,a1.w);
      o2.x = packbf2(a2.x,a2.y); o2.y = packbf2(a2.z,a2.w);
      o2.z = packbf2(a3.x,a3.y); o2.w = packbf2(a3.z,a3.w);
    }
    *(uint4*)(ldsA + ((row*256 + k0*2     ) ^ ((row&7)<<4))) = o;
    *(uint4*)(ldsA + ((row*256 + k0*2 + 16) ^ ((row&7)<<4))) = o2;
  }
  __syncthreads();

  // ---- GEMM1: wave's 16 rows x all 128 cols ----
  f32x4 acc[8];
#pragma unroll
  for (int nt=0;nt<8;++nt) acc[nt] = zf;
  for (int ks=0; ks<4; ++ks){
    int row = wv*16 + lrow;
    bf16x8v a0 = *(const bf16x8v*)(ldsA + ((row*256 + ks*64 + lhi*16) ^ ((row&7)<<4)));
    bf16x8v bb[4];
#pragma unroll
    for (int h=0; h<2; ++h){
#pragma unroll
      for (int j=0;j<4;++j){
        int jj = (h*4+j)*16 + lrow;
        bb[j] = *(const bf16x8v*)(w1t + (size_t)jj*128 + ks*32 + lhi*8);
      }
#pragma unroll
      for (int j=0;j<4;++j)
        acc[h*4+j] = __builtin_amdgcn_mfma_f32_16x16x32_bf16(a0, bb[j], acc[h*4+j], 0,0,0);
    }
  }
  // ---- add b1, LayerNorm stats via shfl over lrow lanes ----
#pragma unroll
  for (int nt=0;nt<8;++nt){
    float bv = lb1[nt*16 + lrow];
#pragma unroll
    for (int r=0;r<4;++r) acc[nt][r] += bv;
  }
  float mu[4], rs[4];
#pragma unroll
  for (int r=0;r<4;++r){
    float s = 0.f, ss = 0.f;
#pragma unroll
    for (int nt=0;nt<8;++nt){ float v = acc[nt][r]; s += v; ss += v*v; }
#pragma unroll
    for (int off=1; off<16; off<<=1){ s += __shfl_xor(s, off, 16); ss += __shfl_xor(ss, off, 16); }
    float m = s*(1.f/128.f);
    mu[r] = m;
    rs[r] = rsqrtf(fmaxf(ss*(1.f/128.f) - m*m, 0.f) + 1e-5f);
  }
  // ---- normalize+affine+silu -> h (overwrite own rows; wave-exclusive) ----
#pragma unroll
  for (int nt=0;nt<8;++nt){
    int col = nt*16 + lrow;
    float gv = lg[col], bv = lbt[col];
#pragma unroll
    for (int r=0;r<4;++r){
      int row = wv*16 + lhi*4 + r;
      float v = (acc[nt][r] - mu[r]) * rs[r] * gv + bv;
      *(bf16*)(ldsA + ((row*256 + col*2) ^ ((row&7)<<4))) = f2bf(silu_f(v));
    }
  }
  __syncthreads();

  // ---- GEMM2: [64x128] @ w2t -> 768 cols, wave cols [wv*192, wv*192+192) ----
#pragma unroll
  for (int c=0;c<3;++c){
    f32x4 a2[4][4];                           // [p][mt]
#pragma unroll
    for (int p=0;p<4;++p)
#pragma unroll
    for (int mt=0;mt<4;++mt) a2[p][mt] = zf;
    for (int ks=0; ks<4; ++ks){
      bf16x8v aA[4];
#pragma unroll
      for (int mt=0;mt<4;++mt){
        int row = mt*16 + lrow;
        aA[mt] = *(const bf16x8v*)(ldsA + ((row*256 + ks*64 + lhi*16) ^ ((row&7)<<4)));
      }
      bf16x8v bb[4];
#pragma unroll
      for (int p=0;p<4;++p){
        int jj = wv*192 + c*64 + p*16 + lrow;
        bb[p] = *(const bf16x8v*)(w2t + (size_t)jj*128 + ks*32 + lhi*8);
      }
#pragma unroll
      for (int p=0;p<4;++p)
#pragma unroll
      for (int mt=0;mt<4;++mt)
        a2[p][mt] = __builtin_amdgcn_mfma_f32_16x16x32_bf16(aA[mt], bb[p], a2[p][mt], 0,0,0);
    }
    // epilogue: rad = acc + b2
#pragma unroll
    for (int p=0;p<4;++p){
      int col = wv*192 + c*64 + p*16 + lrow;
      float bc = b2[col];
#pragma unroll
      for (int mt=0;mt<4;++mt)
#pragma unroll
      for (int r=0;r<4;++r){
        int el = mt*16 + lhi*4 + r;
        if (el < evalid)
          ro[(size_t)(e0+el)*768 + col] = f2bf(a2[p][mt][r] + bc);
      }
    }
  }
}

// ---------------------------------------------------------------------------
// SO2 conv: 3 streaming GEMM kernels (split structure, round-12 verified).
// ---------------------------------------------------------------------------

// G0: [32e x 384] @ w0t -> N0 cols; conv1 writes gate (silu'd) to glb.
template<bool CONV1>
__global__ __launch_bounds__(256, 3)
void k_g0(const bf16* __restrict__ rad, const bf16* __restrict__ msg_in,
          const bf16* __restrict__ w0t, const float* __restrict__ b0,
          bf16* __restrict__ msg, bf16* __restrict__ glb)
{
  __shared__ char ldsA[24576];        // [32][768B] swizzled
  __shared__ bf16 gls[8192];          // [32][256] gate (conv1)
  const int t = threadIdx.x;
  const int lane = t & 63, wv = t >> 6;
  const int lrow = lane & 15, lhi = lane >> 4;
  const int e0 = blockIdx.x * 32;
  int evalid = EDGES - e0; if (evalid > 32) evalid = 32;
  const uint4 z4 = {0u,0u,0u,0u};
  const f32x4 zf = {0.f,0.f,0.f,0.f};

  // stage A0
#pragma unroll
  for (int i=0;i<6;++i){
    int ch = t + 256*i;                       // 0..1535
    int row = ch / 48, k0 = (ch % 48) * 8;
    int e = e0 + row;
    uint4 mz = z4, rz = z4;
    if (e < EDGES){
      mz = *(const uint4*)(msg_in + (size_t)e*1152 + k0);
      rz = *(const uint4*)(rad    + (size_t)e*768  + k0);
    }
    *(uint4*)(ldsA + ((row*768 + k0*2) ^ ((row&7)<<4))) = mulp(mz, rz);
  }
  __syncthreads();

  constexpr int NT0 = CONV1 ? 10 : 6;
  constexpr int HB  = NT0 / 2;
  const int wcol0 = wv * NT0 * 16;
  f32x4 acc0[NT0][2];
#pragma unroll
  for (int nt=0; nt<NT0; ++nt){ acc0[nt][0]=zf; acc0[nt][1]=zf; }
  for (int ks=0; ks<12; ++ks){
    bf16x8v a0 = *(const bf16x8v*)(ldsA + (((lrow   )*768 + ks*64 + lhi*16) ^ ((lrow&7)<<4)));
    bf16x8v a1 = *(const bf16x8v*)(ldsA + (((16+lrow)*768 + ks*64 + lhi*16) ^ ((lrow&7)<<4)));
#pragma unroll
    for (int h=0; h<2; ++h){
      bf16x8v bb[HB];
#pragma unroll
      for (int j=0;j<HB;++j){
        int coln = wcol0 + (h*HB+j)*16 + lrow;
        bb[j] = *(const bf16x8v*)(w0t + (size_t)coln*384 + ks*32 + lhi*8);
      }
#pragma unroll
      for (int j=0;j<HB;++j){
        int nt = h*HB+j;
        acc0[nt][0] = __builtin_amdgcn_mfma_f32_16x16x32_bf16(a0, bb[j], acc0[nt][0], 0,0,0);
        acc0[nt][1] = __builtin_amdgcn_mfma_f32_16x16x32_bf16(a1, bb[j], acc0[nt][1], 0,0,0);
      }
    }
  }
  if (CONV1){
#pragma unroll
    for (int nt=0; nt<NT0; ++nt){
      int colb = wcol0 + nt*16;
      if (colb >= 384){
        float bc = b0[colb + lrow];
        int cc = colb + lrow - 384;
#pragma unroll
        for (int mt=0; mt<2; ++mt)
#pragma unroll
        for (int r=0; r<4; ++r){
          int el = mt*16 + lhi*4 + r;
          bf16 gv = f2bf(silu_f(acc0[nt][mt][r] + bc));
          gls[el*256 + cc] = gv;
          if (el < evalid) glb[(size_t)(e0+el)*256 + cc] = gv;
        }
      }
    }
    __syncthreads();                          // gls ready
  }
  // out0 epilogue (rows 0-2)
#pragma unroll
  for (int nt=0; nt<NT0; ++nt){
    int colb = wcol0 + nt*16;
    if (colb < 384){
      int col = colb + lrow;
      int f = col >> 7, c = col & 127;
      float bc = b0[col];
#pragma unroll
      for (int mt=0; mt<2; ++mt)
#pragma unroll
      for (int r=0; r<4; ++r){
        int el = mt*16 + lhi*4 + r;
        if (el < evalid){
          float v = acc0[nt][mt][r] + bc;
          float o;
          if (CONV1) o = (f==0) ? silu_f(v) : v * bf2f(gls[el*256 + (f==2?128:0) + c]);
          else       o = v;
          msg[(size_t)(e0+el)*1152 + col] = f2bf(o);
        }
      }
    }
  }
}

// G1: 16 edges/block, A[32x256] @ w1t -> 512; r/i recombine; gate from glb.
template<bool CONV1>
__global__ __launch_bounds__(256, 3)
void k_g1(const bf16* __restrict__ rad,
          const bf16* __restrict__ w1t,
          bf16* __restrict__ msg, const bf16* __restrict__ glb)
{
  __shared__ char ldsA[16384];        // [32][512B] swizzled
  const int t = threadIdx.x;
  const int lane = t & 63, wv = t >> 6;
  const int lrow = lane & 15, lhi = lane >> 4;
  const int e0 = blockIdx.x * 16;
  const uint4 z4 = {0u,0u,0u,0u};
  const f32x4 zf = {0.f,0.f,0.f,0.f};

  // stage: rows = 2*eL + m
#pragma unroll
  for (int i=0;i<4;++i){
    int ch = t + 256*i;                       // 0..1023
    int row = ch >> 5, k0 = (ch & 31) * 8;
    int e = e0 + (row >> 1);
    uint4 mz = z4, rz = z4;
    if (e < EDGES){
      mz = *(const uint4*)(msg + (size_t)e*1152 + 384 + (row&1)*256 + k0);
      rz = *(const uint4*)(rad + (size_t)e*768  + 384 + k0);
    }
    *(uint4*)(ldsA + ((row*512 + k0*2) ^ ((row&7)<<4))) = mulp(mz, rz);
  }
  __syncthreads();

  f32x4 acc1[4][2][2];
#pragma unroll
  for (int p=0;p<4;++p){ acc1[p][0][0]=zf; acc1[p][0][1]=zf; acc1[p][1][0]=zf; acc1[p][1][1]=zf; }
  for (int ks=0; ks<8; ++ks){
    bf16x8v aA[2];
#pragma unroll
    for (int m2=0; m2<2; ++m2){
      int row = m2*16 + lrow;
      aA[m2] = *(const bf16x8v*)(ldsA + ((row*512 + ks*64 + lhi*16) ^ ((row&7)<<4)));
    }
    bf16x8v br[4], bi[4];
#pragma unroll
    for (int p=0; p<4; ++p){
      int jj = wv*64 + p*16 + lrow;
      br[p] = *(const bf16x8v*)(w1t + (size_t)jj*256       + ks*32 + lhi*8);
      bi[p] = *(const bf16x8v*)(w1t + (size_t)(jj+256)*256 + ks*32 + lhi*8);
    }
#pragma unroll
    for (int p=0; p<4; ++p)
#pragma unroll
    for (int m2=0;m2<2;++m2){
      acc1[p][m2][0] = __builtin_amdgcn_mfma_f32_16x16x32_bf16(aA[m2], br[p], acc1[p][m2][0], 0,0,0);
      acc1[p][m2][1] = __builtin_amdgcn_mfma_f32_16x16x32_bf16(aA[m2], bi[p], acc1[p][m2][1], 0,0,0);
    }
  }
  // epilogue rows 3-6
#pragma unroll
  for (int p=0;p<4;++p)
#pragma unroll
  for (int m2=0;m2<2;++m2)
#pragma unroll
  for (int re=0;re<2;++re){
    int elL = m2*8 + lhi*2 + re;              // 0..15
    int e = e0 + elL;
    if (e < EDGES){
      float r0 = acc1[p][m2][0][2*re+0], r1 = acc1[p][m2][0][2*re+1];
      float i0 = acc1[p][m2][1][2*re+0], i1 = acc1[p][m2][1][2*re+1];
      float o0 = r0 - i1, o1 = r1 + i0;
      int jj = wv*64 + p*16 + lrow;
      if (CONV1){ float g = bf2f(glb[(size_t)e*256 + jj]); o0 *= g; o1 *= g; }
      size_t base = (size_t)e*1152;
      msg[base + 384 + jj] = f2bf(o0);
      msg[base + 640 + jj] = f2bf(o1);
    }
  }
}

// G2: 32 edges/block, A[64x128] @ w2t -> 256; r/i recombine; gate from glb.
template<bool CONV1>
__global__ __launch_bounds__(256, 3)
void k_g2(const bf16* __restrict__ rad,
          const bf16* __restrict__ w2t,
          bf16* __restrict__ msg, const bf16* __restrict__ glb)
{
  __shared__ char ldsA[16384];        // [64][256B] swizzled
  const int t = threadIdx.x;
  const int lane = t & 63, wv = t >> 6;
  const int lrow = lane & 15, lhi = lane >> 4;
  const int e0 = blockIdx.x * 32;
  const uint4 z4 = {0u,0u,0u,0u};
  const f32x4 zf = {0.f,0.f,0.f,0.f};

#pragma unroll
  for (int i=0;i<4;++i){
    int ch = t + 256*i;                       // 0..1023
    int row = ch >> 4, k0 = (ch & 15) * 8;
    int e = e0 + (row >> 1);
    uint4 mz = z4, rz = z4;
    if (e < EDGES){
      mz = *(const uint4*)(msg + (size_t)e*1152 + 896 + (row&1)*128 + k0);
      rz = *(const uint4*)(rad + (size_t)e*768  + 640 + k0);
    }
    *(uint4*)(ldsA + ((row*256 + k0*2) ^ ((row&7)<<4))) = mulp(mz, rz);
  }
  __syncthreads();

  f32x4 acc2[2][4][2];
#pragma unroll
  for (int p=0;p<2;++p)
#pragma unroll
  for (int mt=0;mt<4;++mt){ acc2[p][mt][0]=zf; acc2[p][mt][1]=zf; }
  for (int ks=0; ks<4; ++ks){
    bf16x8v aA[4];
#pragma unroll
    for (int mt=0;mt<4;++mt){
      int row = mt*16 + lrow;
      aA[mt] = *(const bf16x8v*)(ldsA + ((row*256 + ks*64 + lhi*16) ^ ((row&7)<<4)));
    }
    bf16x8v br2[2], bi2[2];
#pragma unroll
    for (int p=0;p<2;++p){
      int jj = wv*32 + p*16 + lrow;
      br2[p] = *(const bf16x8v*)(w2t + (size_t)jj*128       + ks*32 + lhi*8);
      bi2[p] = *(const bf16x8v*)(w2t + (size_t)(jj+128)*128 + ks*32 + lhi*8);
    }
#pragma unroll
    for (int p=0;p<2;++p)
#pragma unroll
    for (int mt=0;mt<4;++mt){
      acc2[p][mt][0] = __builtin_amdgcn_mfma_f32_16x16x32_bf16(aA[mt], br2[p], acc2[p][mt][0], 0,0,0);
      acc2[p][mt][1] = __builtin_amdgcn_mfma_f32_16x16x32_bf16(aA[mt], bi2[p], acc2[p][mt][1], 0,0,0);
    }
  }
  // epilogue rows 7,8
#pragma unroll
  for (int p=0;p<2;++p)
#pragma unroll
  for (int mt=0;mt<4;++mt)
#pragma unroll
  for (int re=0;re<2;++re){
    int el = mt*8 + lhi*2 + re;               // 0..31
    int e = e0 + el;
    if (e < EDGES){
      float r0 = acc2[p][mt][0][2*re+0], r1 = acc2[p][mt][0][2*re+1];
      float i0 = acc2[p][mt][1][2*re+0], i1 = acc2[p][mt][1][2*re+1];
      float o0 = r0 - i1, o1 = r1 + i0;
      int jj = wv*32 + p*16 + lrow;
      if (CONV1){ float g = bf2f(glb[(size_t)e*256 + 128 + jj]); o0 *= g; o1 *= g; }
      size_t base = (size_t)e*1152;
      msg[base + 896  + jj] = f2bf(o0);
      msg[base + 1024 + jj] = f2bf(o1);
    }
  }
}

// ---------------------------------------------------------------------------
// K5: out[dst] += wigner_inv[e] @ msg[e]
// ---------------------------------------------------------------------------
__global__ __launch_bounds__(128)
void k_wiginv_scatter(const bf16* __restrict__ msg, const int* __restrict__ eidx,
                      const float* __restrict__ wiginv, float* __restrict__ out)
{
  const int e = blockIdx.x;
  const int c = threadIdx.x;
  __shared__ float wl[81];
  if (c < 81) wl[c] = wiginv[e*81 + c];
  float m[9];
#pragma unroll
  for (int r=0;r<9;++r) m[r] = bf2f(msg[(size_t)e*1152 + r*128 + c]);
  const int dst = eidx[EDGES + e];
  __syncthreads();
  float* op = out + (size_t)dst*1152 + c;
#pragma unroll
  for (int f=0;f<9;++f){
    float a = 0.f;
#pragma unroll
    for (int r=0;r<9;++r) a = fmaf(wl[f*9+r], m[r], a);
    atomicAdd(op + f*128, a);
  }
}

// ---------------------------------------------------------------------------
extern "C" void kernel_launch(void* const* d_in, const int* in_sizes, int n_in,
                              void* d_out, int out_size, void* d_ws, size_t ws_size,
                              hipStream_t stream)
{
  const float* x       = (const float*)d_in[0];
  const float* x_edge  = (const float*)d_in[1];
  const int*   eidx    = (const int*)  d_in[3];
  const float* wig     = (const float*)d_in[4];
  const float* wiginv  = (const float*)d_in[5];
  const float* r1w1    = (const float*)d_in[6];
  const float* r1b1    = (const float*)d_in[7];
  const float* r1g     = (const float*)d_in[8];
  const float* r1bt    = (const float*)d_in[9];
  const float* r1w2    = (const float*)d_in[10];
  const float* r1b2    = (const float*)d_in[11];
  const float* c1w0    = (const float*)d_in[12];
  const float* c1b0    = (const float*)d_in[13];
  const float* c1w1    = (const float*)d_in[14];
  const float* c1w2    = (const float*)d_in[15];
  const float* r2w1    = (const float*)d_in[16];
  const float* r2b1    = (const float*)d_in[17];
  const float* r2g     = (const float*)d_in[18];
  const float* r2bt    = (const float*)d_in[19];
  const float* r2w2    = (const float*)d_in[20];
  const float* r2b2    = (const float*)d_in[21];
  const float* c2w0    = (const float*)d_in[22];
  const float* c2b0    = (const float*)d_in[23];
  const float* c2w1    = (const float*)d_in[24];
  const float* c2w2    = (const float*)d_in[25];
  float* out = (float*)d_out;

  // ws: msg 115.2 | rad 76.8 | conv wts 1.44 | radial wts 0.46 | glb 25.6 = ~219.5MB
  char* ws = (char*)d_ws;
  bf16* msg   = (bf16*)(ws);
  bf16* rad   = (bf16*)(ws + (size_t)115200000);
  bf16* w0t1  = (bf16*)(ws + (size_t)192000000);   // 640x384
  bf16* w1t1  = (bf16*)(ws + (size_t)192491520);   // 512x256
  bf16* w2t1  = (bf16*)(ws + (size_t)192753664);   // 256x128
  bf16* w0t2  = (bf16*)(ws + (size_t)192819200);   // 384x384
  bf16* w1t2  = (bf16*)(ws + (size_t)193114112);   // 512x256
  bf16* w2t2  = (bf16*)(ws + (size_t)193376256);   // 256x128
  bf16* rw1tA = (bf16*)(ws + (size_t)193441792);   // 128x128
  bf16* rw2tA = (bf16*)(ws + (size_t)193474560);   // 768x128
  bf16* rw1tB = (bf16*)(ws + (size_t)193671168);   // 128x128
  bf16* rw2tB = (bf16*)(ws + (size_t)193703936);   // 768x128
  bf16* glb   = (bf16*)(ws + (size_t)193900544);   // 50000x256 = 25.6MB

  k_wT<<<dim3(12,20),256,0,stream>>>(c1w0, w0t1, 384, 640);
  k_wT<<<dim3( 8,16),256,0,stream>>>(c1w1, w1t1, 256, 512);
  k_wT<<<dim3( 4, 8),256,0,stream>>>(c1w2, w2t1, 128, 256);
  k_wT<<<dim3(12,12),256,0,stream>>>(c2w0, w0t2, 384, 384);
  k_wT<<<dim3( 8,16),256,0,stream>>>(c2w1, w1t2, 256, 512);
  k_wT<<<dim3( 4, 8),256,0,stream>>>(c2w2, w2t2, 128, 256);
  k_wT<<<dim3( 4, 4),256,0,stream>>>(r1w1, rw1tA, 128, 128);
  k_wT<<<dim3( 4,24),256,0,stream>>>(r1w2, rw2tA, 128, 768);
  k_wT<<<dim3( 4, 4),256,0,stream>>>(r2w1, rw1tB, 128, 128);
  k_wT<<<dim3( 4,24),256,0,stream>>>(r2w2, rw2tB, 128, 768);

  hipMemsetAsync(d_out, 0, (size_t)out_size*sizeof(float), stream);
  k_gather_rot<<<EDGES, 128, 0, stream>>>(x, eidx, wig, msg);

  k_radial_mfma<<<(EDGES+63)/64, 256, 0, stream>>>(x_edge, rw1tA, r1b1, r1g, r1bt, rw2tA, r1b2, rad);
  k_g0<true ><<<(EDGES+31)/32, 256, 0, stream>>>(rad, msg, w0t1, c1b0, msg, glb);
  k_g1<true ><<<(EDGES+15)/16, 256, 0, stream>>>(rad, w1t1, msg, glb);
  k_g2<true ><<<(EDGES+31)/32, 256, 0, stream>>>(rad, w2t1, msg, glb);

  k_radial_mfma<<<(EDGES+63)/64, 256, 0, stream>>>(x_edge, rw1tB, r2b1, r2g, r2bt, rw2tB, r2b2, rad);
  k_g0<false><<<(EDGES+31)/32, 256, 0, stream>>>(rad, msg, w0t2, c2b0, msg, glb);
  k_g1<false><<<(EDGES+15)/16, 256, 0, stream>>>(rad, w1t2, msg, glb);
  k_g2<false><<<(EDGES+31)/32, 256, 0, stream>>>(rad, w2t2, msg, glb);

  k_wiginv_scatter<<<EDGES, 128, 0, stream>>>(msg, eidx, wiginv, out);
}